// Round 10
// baseline (556.439 us; speedup 1.0000x reference)
//
#include <hip/hip_runtime.h>
#include <hip/hip_bf16.h>

// ============================================================================
// NexToU encoder block, MFMA bf16, [voxel][channel] layout. Round 10:
// r6-proven convs + FFN kernels with W read per-lane from L2 (weights are
// 144KB, read-only, L2-resident for all 2048 blocks):
//  - ffn_k: no W LDS staging, ZERO barriers in main loop, LDS 21.5KB
//  - ffn_stats_k: no Bs staging, 2 barriers/quarter only (ps reduce)
// ============================================================================

typedef __hip_bfloat16 bf16;
typedef __attribute__((ext_vector_type(8))) short short8;
typedef __attribute__((ext_vector_type(4))) float f4;
typedef __attribute__((ext_vector_type(2))) unsigned uint2v;

#define DEV static __device__ __forceinline__

constexpr int Sq  = 131072;   // D*H*W
constexpr int NVq = 262144;   // B*S

DEV float bu2f(unsigned short u) { return __uint_as_float(((unsigned)u) << 16); }
DEV unsigned short f2bu(float f) {
    unsigned i = __float_as_uint(f);
    unsigned r = i + 0x7FFFu + ((i >> 16) & 1u);   // RNE (finite inputs only)
    return (unsigned short)(r >> 16);
}
DEV unsigned cvtpk(float a, float b) {   // {lo=cvt(a), hi=cvt(b)}
    unsigned r;
    asm("v_cvt_pk_bf16_f32 %0, %1, %2" : "=v"(r) : "v"(a), "v"(b));
    return r;
}
DEV void glds16(const void* g, void* l) {
    __builtin_amdgcn_global_load_lds(
        (const __attribute__((address_space(1))) unsigned*)g,
        (__attribute__((address_space(3))) unsigned*)l, 16, 0, 0);
}

// ---------------------------------------------------------------------------
// MFMA conv (round-6 proven, verbatim): Y[v][n] = sum_k A[v][k]*W[n][k]+bias.
// AMODE: 0 plain gload_lds; 2 per-(b,c) affine+lrelu (fc2);
//        4 dual-stream concat (y1-affine | xj-plain) for conv g.
// ---------------------------------------------------------------------------
template<int CIRB, int KP, int CO, int BN, int AMODE, bool PERB>
__global__ __launch_bounds__(256)
void conv_k(const char* __restrict__ A0, const char* __restrict__ A1,
            const char* __restrict__ Wb, const float* __restrict__ bias,
            const float* __restrict__ cfA, const float* __restrict__ cfB,
            bf16* __restrict__ Y, float* __restrict__ part)
{
    constexpr int NSTEP = KP / 64;
    constexpr int NF = BN / 16;
    constexpr int BI = BN / 8;
    __shared__ __align__(16) char smem[16384 + BN * 128];
    char* As = smem;
    char* Bs = smem + 16384;

    const int tid = threadIdx.x;
    const int lane = tid & 63, wid = tid >> 6, l16 = lane & 15, lhi = lane >> 4;
    const int gm = blockIdx.x, gy = blockIdx.y;
    const int v0 = gm * 128;
    const int b = gm >> 10;
    const int n0g = gy * BN;

    f4 acc[2][NF];
#pragma unroll
    for (int nf = 0; nf < NF; ++nf) {
        float bb = bias[n0g + nf * 16 + l16];
        f4 t = {bb, bb, bb, bb};
        acc[0][nf] = t; acc[1][nf] = t;
    }

    for (int s = 0; s < NSTEP; ++s) {
        for (int i = wid; i < BI; i += 4) {
            int o = i * 8 + (lane >> 3);
            glds16(Wb + (size_t)(n0g + o) * (KP * 2) + s * 128 + (((lane & 7) ^ (o & 7)) << 4),
                   Bs + i * 1024);
        }
        if constexpr (AMODE == 0) {
            for (int i = wid; i < 16; i += 4) {
                int r = i * 8 + (lane >> 3);
                glds16(A0 + (size_t)(v0 + r) * CIRB + s * 128 + (((lane & 7) ^ (r & 7)) << 4),
                       As + i * 1024);
            }
        } else {
#pragma unroll
            for (int j = 0; j < 4; ++j) {
                int idx = tid + 256 * j;
                int v = idx >> 3, u = idx & 7;
                int k8 = s * 8 + u;
                short8 hh;
                if constexpr (AMODE == 2) {        // fc2: per-(b,c) affine+lrelu
                    short8 raw = *(const short8*)(A0 + (size_t)(v0 + v) * CIRB + k8 * 16);
                    int cb = b * KP + k8 * 8;
                    f4 a0 = *(const f4*)(cfA + cb), a1 = *(const f4*)(cfA + cb + 4);
                    f4 d0 = *(const f4*)(cfB + cb), d1 = *(const f4*)(cfB + cb + 4);
#pragma unroll
                    for (int e = 0; e < 4; ++e) {
                        float t0 = fmaf(a0[e], bu2f((unsigned short)raw[e]),     d0[e]);
                        float t1 = fmaf(a1[e], bu2f((unsigned short)raw[e + 4]), d1[e]);
                        t0 = fmaxf(t0, 0.2f * t0);
                        t1 = fmaxf(t1, 0.2f * t1);
                        hh[e] = (short)f2bu(t0); hh[e + 4] = (short)f2bu(t1);
                    }
                } else {                           // conv g: y1-affine | xj-plain
                    if (k8 < 12) {
                        short8 raw = *(const short8*)(A0 + (size_t)(v0 + v) * 192 + k8 * 16);
                        int cb = k8 * 8;
                        f4 a0 = *(const f4*)(cfA + cb), a1 = *(const f4*)(cfA + cb + 4);
                        f4 d0 = *(const f4*)(cfB + cb), d1 = *(const f4*)(cfB + cb + 4);
#pragma unroll
                        for (int e = 0; e < 4; ++e) {
                            hh[e]     = (short)f2bu(fmaf(a0[e], bu2f((unsigned short)raw[e]),     d0[e]));
                            hh[e + 4] = (short)f2bu(fmaf(a1[e], bu2f((unsigned short)raw[e + 4]), d1[e]));
                        }
                    } else {
                        hh = *(const short8*)(A1 + (size_t)(v0 + v) * 192 + (k8 - 12) * 16);
                    }
                }
                *(short8*)(As + v * 128 + ((u ^ (v & 7)) << 4)) = hh;
            }
        }
        __syncthreads();
#pragma unroll
        for (int ks = 0; ks < 2; ++ks) {
            int kg = ks * 4 + lhi;
            short8 av[2];
#pragma unroll
            for (int mf = 0; mf < 2; ++mf) {
                int v = wid * 32 + mf * 16 + l16;
                av[mf] = *(const short8*)(As + v * 128 + ((kg ^ (v & 7)) << 4));
            }
#pragma unroll
            for (int nf = 0; nf < NF; ++nf) {
                int o = nf * 16 + l16;
                short8 bv = *(const short8*)(Bs + o * 128 + ((kg ^ (o & 7)) << 4));
                acc[0][nf] = __builtin_amdgcn_mfma_f32_16x16x32_bf16(av[0], bv, acc[0][nf], 0, 0, 0);
                acc[1][nf] = __builtin_amdgcn_mfma_f32_16x16x32_bf16(av[1], bv, acc[1][nf], 0, 0, 0);
            }
        }
        __syncthreads();
    }

#pragma unroll
    for (int mf = 0; mf < 2; ++mf) {
        int vb = v0 + wid * 32 + mf * 16 + lhi * 4;
#pragma unroll
        for (int nf = 0; nf < NF; ++nf) {
            int n = n0g + nf * 16 + l16;
#pragma unroll
            for (int r = 0; r < 4; ++r) {
                bf16 o; *(unsigned short*)&o = f2bu(acc[mf][nf][r]);
                Y[(size_t)(vb + r) * CO + n] = o;
            }
        }
    }
    float* ps = (float*)smem;
#pragma unroll
    for (int nf = 0; nf < NF; ++nf) {
        float sm = 0.f, sq = 0.f;
#pragma unroll
        for (int mf = 0; mf < 2; ++mf)
#pragma unroll
            for (int r = 0; r < 4; ++r) {
                float v = acc[mf][nf][r];
                sm += v; sq += v * v;
            }
        sm += __shfl_xor(sm, 16); sq += __shfl_xor(sq, 16);
        sm += __shfl_xor(sm, 32); sq += __shfl_xor(sq, 32);
        if (lane < 16) {
            ps[(wid * 2 + 0) * BN + nf * 16 + lane] = sm;
            ps[(wid * 2 + 1) * BN + nf * 16 + lane] = sq;
        }
    }
    __syncthreads();
    if (tid < BN) {
        float sm = ps[0 * BN + tid] + ps[2 * BN + tid] + ps[4 * BN + tid] + ps[6 * BN + tid];
        float sq = ps[1 * BN + tid] + ps[3 * BN + tid] + ps[5 * BN + tid] + ps[7 * BN + tid];
        int slot = PERB ? (b * 32 + (gm & 31)) : (gm & 63);
        float* pb = part + (size_t)(gy * 64 + slot) * 2 * BN;
        atomicAdd(&pb[tid], sm);
        atomicAdd(&pb[BN + tid], sq);
    }
}

// ---------------------------------------------------------------------------
// ffn_stats_k (round-10): x2 = A3*y2+B3+xT per-fragment in regs, write
// global; 4 stats-only GEMM quarters with W1 fragments read per-lane from
// global (L2-resident). LDS = ps only (3KB).
// ---------------------------------------------------------------------------
__global__ __launch_bounds__(256)
void ffn_stats_k(const char* __restrict__ y2, const char* __restrict__ xT,
                 const float* __restrict__ cfA, const float* __restrict__ cfB,
                 const float* __restrict__ biasf1, const char* __restrict__ Wf1,
                 char* __restrict__ x2, float* __restrict__ part)
{
    __shared__ float ps[8 * 96];

    const int tid = threadIdx.x;
    const int lane = tid & 63, wid = tid >> 6, l16 = lane & 15, lhi = lane >> 4;
    const int gm = blockIdx.x;
    const int v0 = gm * 128;

    short8 afr[2][3];
#pragma unroll
    for (int mf = 0; mf < 2; ++mf)
#pragma unroll
        for (int ks = 0; ks < 3; ++ks) {
            int v = v0 + wid * 32 + mf * 16 + l16;
            int kg = ks * 4 + lhi, cb = kg * 8;
            short8 yv = *(const short8*)(y2 + (size_t)v * 192 + kg * 16);
            short8 xv = *(const short8*)(xT + (size_t)v * 192 + kg * 16);
            f4 a0 = *(const f4*)(cfA + cb), a1 = *(const f4*)(cfA + cb + 4);
            f4 d0 = *(const f4*)(cfB + cb), d1 = *(const f4*)(cfB + cb + 4);
            short8 o;
#pragma unroll
            for (int e = 0; e < 4; ++e) {
                float t0 = fmaf(a0[e], bu2f((unsigned short)yv[e]),     d0[e]) + bu2f((unsigned short)xv[e]);
                float t1 = fmaf(a1[e], bu2f((unsigned short)yv[e + 4]), d1[e]) + bu2f((unsigned short)xv[e + 4]);
                o[e]     = (short)f2bu(t0);
                o[e + 4] = (short)f2bu(t1);
            }
            afr[mf][ks] = o;
            *(short8*)(x2 + (size_t)v * 192 + kg * 16) = o;
        }

    for (int q = 0; q < 4; ++q) {
        f4 acc[2][6];
#pragma unroll
        for (int nf = 0; nf < 6; ++nf) {
            float bb = biasf1[q * 96 + nf * 16 + l16];
            f4 t = {bb, bb, bb, bb};
            acc[0][nf] = t; acc[1][nf] = t;
        }
#pragma unroll
        for (int ks = 0; ks < 3; ++ks) {
            int kg = ks * 4 + lhi;
#pragma unroll
            for (int nf = 0; nf < 6; ++nf) {
                int o = q * 96 + nf * 16 + l16;
                short8 bv = *(const short8*)(Wf1 + (size_t)o * 192 + kg * 16);
                acc[0][nf] = __builtin_amdgcn_mfma_f32_16x16x32_bf16(afr[0][ks], bv, acc[0][nf], 0, 0, 0);
                acc[1][nf] = __builtin_amdgcn_mfma_f32_16x16x32_bf16(afr[1][ks], bv, acc[1][nf], 0, 0, 0);
            }
        }
        if (q) __syncthreads();    // ps reuse guard from previous quarter
#pragma unroll
        for (int nf = 0; nf < 6; ++nf) {
            float sm = 0.f, sq = 0.f;
#pragma unroll
            for (int mf = 0; mf < 2; ++mf)
#pragma unroll
                for (int r = 0; r < 4; ++r) {
                    float v = acc[mf][nf][r];
                    sm += v; sq += v * v;
                }
            sm += __shfl_xor(sm, 16); sq += __shfl_xor(sq, 16);
            sm += __shfl_xor(sm, 32); sq += __shfl_xor(sq, 32);
            if (lane < 16) {
                ps[(wid * 2 + 0) * 96 + nf * 16 + lane] = sm;
                ps[(wid * 2 + 1) * 96 + nf * 16 + lane] = sq;
            }
        }
        __syncthreads();
        if (tid < 96) {
            float sm = ps[0 * 96 + tid] + ps[2 * 96 + tid] + ps[4 * 96 + tid] + ps[6 * 96 + tid];
            float sq = ps[1 * 96 + tid] + ps[3 * 96 + tid] + ps[5 * 96 + tid] + ps[7 * 96 + tid];
            float* pb = part + (size_t)(q * 64 + (gm & 63)) * 192;
            atomicAdd(&pb[tid], sm);
            atomicAdd(&pb[96 + tid], sq);
        }
    }
}

// ---------------------------------------------------------------------------
// ffn_k (round-10): fused f1+lrelu+BNf1+f2. x2 frags in regs; W fragments
// read per-lane from global (L2); zbuf wave-private [v][144B], lgkm-only
// sync. ZERO barriers in the chunk loop. LDS 21.5KB.
// ---------------------------------------------------------------------------
__global__ __launch_bounds__(256)
void ffn_k(const char* __restrict__ x2, const float* __restrict__ cfA4,
           const float* __restrict__ cfB4, const float* __restrict__ biasf2,
           const char* __restrict__ Wf1, const char* __restrict__ Wf2,
           bf16* __restrict__ y4, float* __restrict__ part)
{
    __shared__ __align__(16) char zb[128 * 144];       // 18432
    __shared__ float ps[8 * 96];                       // 3072

    const int tid = threadIdx.x;
    const int lane = tid & 63, wid = tid >> 6, l16 = lane & 15, lhi = lane >> 4;
    const int gm = blockIdx.x;
    const int v0 = gm * 128;

    short8 xfr[2][3];
#pragma unroll
    for (int nt = 0; nt < 2; ++nt)
#pragma unroll
        for (int ks = 0; ks < 3; ++ks)
            xfr[nt][ks] = *(const short8*)(x2 + (size_t)(v0 + wid * 32 + nt * 16 + l16) * 192
                                           + (ks * 4 + lhi) * 16);

    f4 accY[2][6];
#pragma unroll
    for (int nf = 0; nf < 6; ++nf) {
        float bb = biasf2[nf * 16 + l16];
        f4 t = {bb, bb, bb, bb};
        accY[0][nf] = t; accY[1][nf] = t;
    }

    for (int nc = 0; nc < 6; ++nc) {
        // GEMM1 (swapped): z rows = y3-channel, cols = voxel.
        // W1 fragments per-lane from global (L2-hot, shared by all blocks).
        f4 z[4][2];
#pragma unroll
        for (int mt = 0; mt < 4; ++mt) { z[mt][0] = f4{0,0,0,0}; z[mt][1] = f4{0,0,0,0}; }
#pragma unroll
        for (int ks = 0; ks < 3; ++ks) {
            int kg = ks * 4 + lhi;
#pragma unroll
            for (int mt = 0; mt < 4; ++mt) {
                int o = nc * 64 + mt * 16 + l16;
                short8 wv = *(const short8*)(Wf1 + (size_t)o * 192 + kg * 16);
                z[mt][0] = __builtin_amdgcn_mfma_f32_16x16x32_bf16(wv, xfr[0][ks], z[mt][0], 0, 0, 0);
                z[mt][1] = __builtin_amdgcn_mfma_f32_16x16x32_bf16(wv, xfr[1][ks], z[mt][1], 0, 0, 0);
            }
        }
        // lrelu(A4*z+B4') -> zbuf (wave-private rows)
#pragma unroll
        for (int mt = 0; mt < 4; ++mt) {
            int ch = nc * 64 + mt * 16 + lhi * 4;
            f4 a = *(const f4*)(cfA4 + ch);
            f4 bb = *(const f4*)(cfB4 + ch);
#pragma unroll
            for (int nt = 0; nt < 2; ++nt) {
                int v = wid * 32 + nt * 16 + l16;
                float t0 = fmaf(a[0], z[mt][nt][0], bb[0]); t0 = fmaxf(t0, 0.2f * t0);
                float t1 = fmaf(a[1], z[mt][nt][1], bb[1]); t1 = fmaxf(t1, 0.2f * t1);
                float t2 = fmaf(a[2], z[mt][nt][2], bb[2]); t2 = fmaxf(t2, 0.2f * t2);
                float t3 = fmaf(a[3], z[mt][nt][3], bb[3]); t3 = fmaxf(t3, 0.2f * t3);
                uint2v w; w[0] = cvtpk(t0, t1); w[1] = cvtpk(t2, t3);
                *(uint2v*)(zb + (size_t)v * 144 + mt * 32 + lhi * 8) = w;
            }
        }
        asm volatile("s_waitcnt lgkmcnt(0)" ::: "memory");
        __builtin_amdgcn_sched_barrier(0);
        // GEMM2: accY += z * W2 ; W2 fragments per-lane from global
#pragma unroll
        for (int ks = 0; ks < 2; ++ks) {
            int kg = ks * 4 + lhi;
            short8 av[2];
#pragma unroll
            for (int mf = 0; mf < 2; ++mf)
                av[mf] = *(const short8*)(zb + (size_t)(wid * 32 + mf * 16 + l16) * 144 + kg * 16);
#pragma unroll
            for (int nf = 0; nf < 6; ++nf) {
                int o = nf * 16 + l16;
                short8 bv = *(const short8*)(Wf2 + (size_t)o * 768 + nc * 128 + kg * 16);
                accY[0][nf] = __builtin_amdgcn_mfma_f32_16x16x32_bf16(av[0], bv, accY[0][nf], 0, 0, 0);
                accY[1][nf] = __builtin_amdgcn_mfma_f32_16x16x32_bf16(av[1], bv, accY[1][nf], 0, 0, 0);
            }
        }
        // no barrier: zbuf is wave-private; WAR on next chunk's ds_write is
        // ordered by the compiler's lgkmcnt tracking for same-wave LDS ops.
    }

#pragma unroll
    for (int mf = 0; mf < 2; ++mf) {
        int vb = v0 + wid * 32 + mf * 16 + lhi * 4;
#pragma unroll
        for (int nf = 0; nf < 6; ++nf) {
            int n = nf * 16 + l16;
#pragma unroll
            for (int r = 0; r < 4; ++r) {
                bf16 o; *(unsigned short*)&o = f2bu(accY[mf][nf][r]);
                y4[(size_t)(vb + r) * 96 + n] = o;
            }
        }
    }
#pragma unroll
    for (int nf = 0; nf < 6; ++nf) {
        float sm = 0.f, sq = 0.f;
#pragma unroll
        for (int mf = 0; mf < 2; ++mf)
#pragma unroll
            for (int r = 0; r < 4; ++r) {
                float v = accY[mf][nf][r];
                sm += v; sq += v * v;
            }
        sm += __shfl_xor(sm, 16); sq += __shfl_xor(sq, 16);
        sm += __shfl_xor(sm, 32); sq += __shfl_xor(sq, 32);
        if (lane < 16) {
            ps[(wid * 2 + 0) * 96 + nf * 16 + lane] = sm;
            ps[(wid * 2 + 1) * 96 + nf * 16 + lane] = sq;
        }
    }
    __syncthreads();
    if (tid < 96) {
        float sm = ps[0 * 96 + tid] + ps[2 * 96 + tid] + ps[4 * 96 + tid] + ps[6 * 96 + tid];
        float sq = ps[1 * 96 + tid] + ps[3 * 96 + tid] + ps[5 * 96 + tid] + ps[7 * 96 + tid];
        float* pb = part + (size_t)(gm & 63) * 192;
        atomicAdd(&pb[tid], sm);
        atomicAdd(&pb[96 + tid], sq);
    }
}

// ---------------------------------------------------------------------------
// partial sums -> affine coefs  A = g*rsqrt(var+eps), B = be - m*A (+ A*bias)
// ---------------------------------------------------------------------------
__global__ void finalize_k(const float* __restrict__ part, float* __restrict__ cf,
                           const float* __restrict__ g, const float* __restrict__ be,
                           const float* __restrict__ bias,
                           int nStats, int CO, int BN, int perB, float invN)
{
    int s = blockIdx.x * 64 + threadIdx.x;
    if (s >= nStats) return;
    int ch = perB ? (s % CO) : s;
    int bb = perB ? (s / CO) : 0;
    int gy = ch / BN, c = ch - gy * BN;
    int j0 = perB ? bb * 32 : 0, cnt = perB ? 32 : 64;
    float sm = 0.f, sq = 0.f;
    for (int j = 0; j < cnt; ++j) {
        const float* pb = part + (size_t)(gy * 64 + j0 + j) * 2 * BN;
        sm += pb[c]; sq += pb[BN + c];
    }
    float m = sm * invN;
    float var = fmaf(-m, m, sq * invN);
    float A = g[ch] * rsqrtf(var + 1e-5f);
    cf[s] = A;
    float B = fmaf(-m, A, be[ch]);
    if (bias) B = fmaf(A, bias[ch], B);
    cf[1024 + s] = B;
}

// ---------------------------------------------------------------------------
// weight prep: f32 [CO][CI] -> bf16 [CO][KP]
// ---------------------------------------------------------------------------
__global__ void wprep_k(const float* __restrict__ w0, const float* __restrict__ w1,
                        const float* __restrict__ w2, const float* __restrict__ w3,
                        const float* __restrict__ w4, bf16* __restrict__ Wb)
{
    int i = blockIdx.x * 256 + threadIdx.x;     // < 141312
    if (i >= 141312) return;
    const float* src; int r, KP, CI, off;
    if (i < 12288)       { src = w0; r = i;          KP = 128; CI = 96;  off = 0; }
    else if (i < 49152)  { src = w1; r = i - 12288;  KP = 192; CI = 192; off = 12288; }
    else if (i < 67584)  { src = w2; r = i - 49152;  KP = 192; CI = 192; off = 49152; }
    else if (i < 104448) { src = w3; r = i - 67584;  KP = 96;  CI = 96;  off = 67584; }
    else                 { src = w4; r = i - 104448; KP = 384; CI = 384; off = 104448; }
    int o = r / KP, k = r - o * KP;
    float v = (k < CI) ? src[o * CI + k] : 0.f;
    bf16 h; *(unsigned short*)&h = f2bu(v);
    Wb[off + r] = h;
}

// ---------------------------------------------------------------------------
// tin: x f32 [b][c][s] -> xT bf16 [v][96] via LDS transpose
// ---------------------------------------------------------------------------
__global__ __launch_bounds__(256)
void tin_k(const float* __restrict__ x, char* __restrict__ xT)
{
    __shared__ float ldsT[128 * 97];
    const int gm = blockIdx.x, b = gm >> 10, s0 = (gm & 1023) * 128;
    const int t = threadIdx.x;
#pragma unroll
    for (int i = 0; i < 12; ++i) {
        int idx = t + 256 * i;
        int c = idx >> 5, s4 = idx & 31;
        f4 r = *(const f4*)(x + ((size_t)(b * 96 + c) << 17) + s0 + s4 * 4);
#pragma unroll
        for (int j = 0; j < 4; ++j) ldsT[(s4 * 4 + j) * 97 + c] = r[j];
    }
    __syncthreads();
#pragma unroll
    for (int i = 0; i < 6; ++i) {
        int idx = t + 256 * i;
        int r = idx / 12, uc = idx % 12, cb = uc * 8;
        short8 o;
#pragma unroll
        for (int e = 0; e < 8; ++e) o[e] = (short)f2bu(ldsT[r * 97 + cb + e]);
        *(short8*)(xT + (size_t)(b * Sq + s0 + r) * 192 + uc * 16) = o;
    }
}

// ---------------------------------------------------------------------------
// MR pass 1a: dminp[b][h][w][dh][p][c] = raw min over d in half dh, parity p
// ---------------------------------------------------------------------------
__global__ __launch_bounds__(192)
void mr_dmin_k(const char* __restrict__ y1, char* __restrict__ dminp)
{
    const int wq = blockIdx.x >> 1, dh = blockIdx.x & 1;
    const int h = blockIdx.y, b = blockIdx.z;
    const int t = threadIdx.x;
    const int w = wq * 16 + t / 12, uc = t % 12;
    const char* base = y1 + (size_t)(b * Sq + dh * 16 * 4096 + h * 64 + w) * 192 + uc * 16;
    float mn[2][8];
#pragma unroll
    for (int p = 0; p < 2; ++p)
#pragma unroll
        for (int e = 0; e < 8; ++e) mn[p][e] = 1e30f;
#pragma unroll 4
    for (int i = 0; i < 16; ++i) {
        short8 raw = *(const short8*)(base + (size_t)i * (4096 * 192));
        int p = i & 1;
#pragma unroll
        for (int e = 0; e < 8; ++e)
            mn[p][e] = fminf(mn[p][e], bu2f((unsigned short)raw[e]));
    }
#pragma unroll
    for (int p = 0; p < 2; ++p) {
        short8 o;
#pragma unroll
        for (int e = 0; e < 8; ++e) o[e] = (short)f2bu(mn[p][e]);
        *(short8*)(dminp + (size_t)((((b * 64 + h) * 64 + w) * 2 + dh) * 2 + p) * 192 + uc * 16) = o;
    }
}

// ---------------------------------------------------------------------------
// MR pass 1b: hminp[b][d][w][hq][p][c] = raw min over h in quarter hq, parity p
// ---------------------------------------------------------------------------
__global__ __launch_bounds__(192)
void mr_hmin_k(const char* __restrict__ y1, char* __restrict__ hminp)
{
    const int wq = blockIdx.x >> 2, hq = blockIdx.x & 3;
    const int d = blockIdx.y, b = blockIdx.z;
    const int t = threadIdx.x;
    const int w = wq * 16 + t / 12, uc = t % 12;
    const char* base = y1 + (size_t)(b * Sq + d * 4096 + hq * 16 * 64 + w) * 192 + uc * 16;
    float mn[2][8];
#pragma unroll
    for (int p = 0; p < 2; ++p)
#pragma unroll
        for (int e = 0; e < 8; ++e) mn[p][e] = 1e30f;
#pragma unroll 4
    for (int i = 0; i < 16; ++i) {
        short8 raw = *(const short8*)(base + (size_t)i * (64 * 192));
        int p = i & 1;
#pragma unroll
        for (int e = 0; e < 8; ++e)
            mn[p][e] = fminf(mn[p][e], bu2f((unsigned short)raw[e]));
    }
#pragma unroll
    for (int p = 0; p < 2; ++p) {
        short8 o;
#pragma unroll
        for (int e = 0; e < 8; ++e) o[e] = (short)f2bu(mn[p][e]);
        *(short8*)(hminp + (size_t)((((b * 32 + d) * 64 + w) * 4 + hq) * 2 + p) * 192 + uc * 16) = o;
    }
}

// ---------------------------------------------------------------------------
// MR pass 2: xj = A_c * (y1 - min(dminp x2, hminp x4, wmin))
// ---------------------------------------------------------------------------
__global__ __launch_bounds__(256)
void mr_p2_k(const char* __restrict__ y1, const float* __restrict__ cfA,
             const char* __restrict__ dminp, const char* __restrict__ hminp,
             char* __restrict__ xj)
{
    __shared__ __align__(16) char rowb[64 * 96 * 2];
    __shared__ float wlds[2 * 96];
    const int h = blockIdx.x, d = blockIdx.y, b = blockIdx.z;
    const int t = threadIdx.x;

    short8 hv[3];
#pragma unroll
    for (int j = 0; j < 3; ++j) {
        int slot = t + 256 * j;
        int w = slot / 12, uc = slot % 12;
        short8 raw = *(const short8*)(y1 + (size_t)(b * Sq + d * 4096 + h * 64 + w) * 192 + uc * 16);
        hv[j] = raw;
        *(short8*)(rowb + slot * 16) = raw;
    }
    __syncthreads();
    if (t < 192) {
        int p = t / 96, c = t % 96;
        float m = 1e30f;
        for (int w2 = p; w2 < 64; w2 += 2)
            m = fminf(m, bu2f(*(const unsigned short*)(rowb + (w2 * 96 + c) * 2)));
        wlds[t] = m;
    }
    __syncthreads();
#pragma unroll
    for (int j = 0; j < 3; ++j) {
        int slot = t + 256 * j;
        int w = slot / 12, uc = slot % 12, cb = uc * 8;
        const char* dp = dminp + (size_t)((((b * 64 + h) * 64 + w) * 2) * 2 + (d & 1)) * 192 + uc * 16;
        short8 dm0 = *(const short8*)(dp);
        short8 dm1 = *(const short8*)(dp + 384);
        const char* hp = hminp + (size_t)((((b * 32 + d) * 64 + w) * 4) * 2 + (h & 1)) * 192 + uc * 16;
        short8 hm0 = *(const short8*)(hp);
        short8 hm1 = *(const short8*)(hp + 384);
        short8 hm2 = *(const short8*)(hp + 768);
        short8 hm3 = *(const short8*)(hp + 1152);
        f4 a0 = *(const f4*)(cfA + cb), a1 = *(const f4*)(cfA + cb + 4);
        short8 xo;
#pragma unroll
        for (int e = 0; e < 8; ++e) {
            float m = fminf(
                fminf(bu2f((unsigned short)dm0[e]), bu2f((unsigned short)dm1[e])),
                fminf(fminf(fminf(bu2f((unsigned short)hm0[e]), bu2f((unsigned short)hm1[e])),
                            fminf(bu2f((unsigned short)hm2[e]), bu2f((unsigned short)hm3[e]))),
                      wlds[(w & 1) * 96 + cb + e]));
            float A = (e < 4) ? a0[e] : a1[e - 4];
            xo[e] = (short)f2bu(A * (bu2f((unsigned short)hv[j][e]) - m));
        }
        *(short8*)(xj + (size_t)(b * Sq + d * 4096 + h * 64 + w) * 192 + uc * 16) = xo;
    }
}

// ---------------------------------------------------------------------------
// tout: out f32 [b][c][s] = A5*y4 + B5 + x2   (transpose via LDS)
// ---------------------------------------------------------------------------
__global__ __launch_bounds__(256)
void tout_k(const char* __restrict__ y4, const float* __restrict__ cfA,
            const float* __restrict__ cfB, const char* __restrict__ x2,
            float* __restrict__ outp)
{
    __shared__ float ldsT[128 * 97];
    const int gm = blockIdx.x, b = gm >> 10, s0 = (gm & 1023) * 128;
    const int t = threadIdx.x;
#pragma unroll
    for (int i = 0; i < 6; ++i) {
        int idx = t + 256 * i;
        int r = idx / 12, uc = idx % 12, cb = uc * 8;
        size_t vv = (size_t)(b * Sq + s0 + r);
        short8 yv = *(const short8*)(y4 + vv * 192 + uc * 16);
        short8 xv = *(const short8*)(x2 + vv * 192 + uc * 16);
        f4 a0 = *(const f4*)(cfA + cb), a1 = *(const f4*)(cfA + cb + 4);
        f4 d0 = *(const f4*)(cfB + cb), d1 = *(const f4*)(cfB + cb + 4);
#pragma unroll
        for (int e = 0; e < 4; ++e) {
            ldsT[r * 97 + cb + e]     = fmaf(a0[e], bu2f((unsigned short)yv[e]),     d0[e]) + bu2f((unsigned short)xv[e]);
            ldsT[r * 97 + cb + e + 4] = fmaf(a1[e], bu2f((unsigned short)yv[e + 4]), d1[e]) + bu2f((unsigned short)xv[e + 4]);
        }
    }
    __syncthreads();
#pragma unroll
    for (int i = 0; i < 12; ++i) {
        int idx = t + 256 * i;
        int c = idx >> 5, s4 = idx & 31;
        f4 o;
#pragma unroll
        for (int j = 0; j < 4; ++j) o[j] = ldsT[(s4 * 4 + j) * 97 + c];
        *(f4*)(outp + ((size_t)(b * 96 + c) << 17) + s0 + s4 * 4) = o;
    }
}

// ===========================================================================
extern "C" void kernel_launch(void* const* d_in, const int* in_sizes, int n_in,
                              void* d_out, int out_size, void* d_ws, size_t ws_size,
                              hipStream_t stream)
{
    (void)in_sizes; (void)n_in; (void)out_size; (void)ws_size;

    const float* x      = (const float*)d_in[0];
    const float* w_fc1  = (const float*)d_in[1];
    const float* b_fc1  = (const float*)d_in[2];
    const float* g_bn1  = (const float*)d_in[3];
    const float* be_bn1 = (const float*)d_in[4];
    const float* w_g    = (const float*)d_in[5];
    const float* b_g    = (const float*)d_in[6];
    const float* g_in   = (const float*)d_in[7];
    const float* be_in  = (const float*)d_in[8];
    const float* w_fc2  = (const float*)d_in[9];
    const float* b_fc2  = (const float*)d_in[10];
    const float* g_bn2  = (const float*)d_in[11];
    const float* be_bn2 = (const float*)d_in[12];
    const float* w_f1   = (const float*)d_in[13];
    const float* b_f1   = (const float*)d_in[14];
    const float* g_bnf1 = (const float*)d_in[15];
    const float* be_bnf1= (const float*)d_in[16];
    const float* w_f2   = (const float*)d_in[17];
    const float* b_f2   = (const float*)d_in[18];
    const float* g_bnf2 = (const float*)d_in[19];
    const float* be_bnf2= (const float*)d_in[20];
    float* outp = (float*)d_out;

    char* W = (char*)d_ws;
    char* xT    = W;
    char* y1    = W + 50331648ull;
    char* dminp = W + 100663296ull;
    char* hminp = W + 113246208ull;
    char* xj    = W + 125829120ull;
    char* yg    = W + 176160768ull;
    char* y2    = W + 50331648ull;     // reuse y1 slot (y1 dead after conv g)
    char* y4    = W + 201326592ull;
    char* x2    = W + 251658240ull;
    char* M     = W + 301989888ull;
    bf16*  Wb   = (bf16*)M;               // 282624 B
    float* cf   = (float*)(M + 307200);   // 5 slots x 2048 f32
    float* part = (float*)(M + 348160);   // 5 slots x 49152 f32

    hipMemsetAsync(part, 0, 5 * 196608, stream);

    const float invBN = 1.f / (float)NVq, invIN = 1.f / (float)Sq;
    dim3 blk(256);
    float* c1 = cf, *c2 = cf + 2048, *c3 = cf + 4096, *c4 = cf + 6144, *c5 = cf + 8192;
    const char* Wfc1 = (const char*)Wb;
    const char* Wg   = (const char*)Wb + 24576;
    const char* Wfc2 = (const char*)Wb + 98304;
    const char* Wf1  = (const char*)Wb + 135168;
    const char* Wf2  = (const char*)Wb + 208896;

    wprep_k<<<552, blk, 0, stream>>>(w_fc1, w_g, w_fc2, w_f1, w_f2, Wb);
    tin_k<<<2048, blk, 0, stream>>>(x, xT);

    // fc1: 96 -> 96 (plain, gload_lds)
    conv_k<192, 128, 96, 96, 0, false><<<dim3(2048, 1), blk, 0, stream>>>(
        xT, nullptr, Wfc1, b_fc1, nullptr, nullptr, (bf16*)y1, part);
    finalize_k<<<2, 64, 0, stream>>>(part, c1, g_bn1, be_bn1, nullptr, 96, 96, 96, 0, invBN);

    // MRConv on raw y1 (A>0): partial mins, then xj = A*(y1 - min3)
    mr_dmin_k<<<dim3(8, 64, 2), dim3(192), 0, stream>>>(y1, dminp);
    mr_hmin_k<<<dim3(16, 32, 2), dim3(192), 0, stream>>>(y1, hminp);
    mr_p2_k<<<dim3(64, 32, 2), blk, 0, stream>>>(y1, c1, dminp, hminp, xj);

    // grapher conv: concat(y1-affine, xj) 192 -> 192, IN stats per (b,c)
    conv_k<192, 192, 192, 192, 4, true><<<dim3(2048, 1), blk, 0, stream>>>(
        y1, xj, Wg, b_g, c1, c1 + 1024, (bf16*)yg, part + 49152);
    finalize_k<<<6, 64, 0, stream>>>(part + 49152, c2, g_in, be_in, nullptr, 384, 192, 192, 1, invIN);

    // fc2: 192 -> 96, loader = lrelu(A2*yg+B2) per (b,c)
    conv_k<384, 192, 96, 96, 2, false><<<dim3(2048, 1), blk, 0, stream>>>(
        yg, nullptr, Wfc2, b_fc2, c2, c2 + 1024, (bf16*)y2, part + 98304);
    finalize_k<<<2, 64, 0, stream>>>(part + 98304, c3, g_bn2, be_bn2, nullptr, 96, 96, 96, 0, invBN);

    // FFN phase 1: x2 = A3*y2+B3+xT (write) + f1 stats-only -> BNf1 partials
    ffn_stats_k<<<2048, blk, 0, stream>>>(y2, xT, c3, c3 + 1024, b_f1, Wf1, x2, part + 147456);
    finalize_k<<<6, 64, 0, stream>>>(part + 147456, c4, g_bnf1, be_bnf1, b_f1, 384, 384, 96, 0, invBN);

    // FFN phase 2: fused f1+lrelu+f2 -> y4 + BNf2 partials
    ffn_k<<<2048, blk, 0, stream>>>(x2, c4, c4 + 1024, b_f2, Wf1, Wf2, (bf16*)y4, part + 196608);
    finalize_k<<<2, 64, 0, stream>>>(part + 196608, c5, g_bnf2, be_bnf2, nullptr, 96, 96, 96, 0, invBN);

    tout_k<<<2048, blk, 0, stream>>>(y4, c5, c5 + 1024, x2, outp);
}

// Round 11
// 536.211 us; speedup vs baseline: 1.0377x; 1.0377x over previous
//
#include <hip/hip_runtime.h>
#include <hip/hip_bf16.h>

// ============================================================================
// NexToU encoder block, MFMA bf16, [voxel][channel] layout. Round 11:
// r9 base (best ~455us) + Grapher stats-recompute fusion (r6 FFN pattern):
//   g_stats_k : hx-frags in regs -> full GEMM stats-only -> IN partials
//   g_fused_k : fused convg+IN+lrelu+fc2 via 64-ch chunks (yg never in HBM)
// ffn kernels = r9 (proven); convs = r6 (proven).
// ============================================================================

typedef __hip_bfloat16 bf16;
typedef __attribute__((ext_vector_type(8))) short short8;
typedef __attribute__((ext_vector_type(4))) float f4;
typedef __attribute__((ext_vector_type(2))) unsigned uint2v;

#define DEV static __device__ __forceinline__

constexpr int Sq  = 131072;   // D*H*W
constexpr int NVq = 262144;   // B*S

DEV float bu2f(unsigned short u) { return __uint_as_float(((unsigned)u) << 16); }
DEV unsigned short f2bu(float f) {
    unsigned i = __float_as_uint(f);
    unsigned r = i + 0x7FFFu + ((i >> 16) & 1u);   // RNE (finite inputs only)
    return (unsigned short)(r >> 16);
}
DEV unsigned cvtpk(float a, float b) {   // {lo=cvt(a), hi=cvt(b)}
    unsigned r;
    asm("v_cvt_pk_bf16_f32 %0, %1, %2" : "=v"(r) : "v"(a), "v"(b));
    return r;
}
DEV void glds16(const void* g, void* l) {
    __builtin_amdgcn_global_load_lds(
        (const __attribute__((address_space(1))) unsigned*)g,
        (__attribute__((address_space(3))) unsigned*)l, 16, 0, 0);
}

// ---------------------------------------------------------------------------
// MFMA conv (round-6 proven, used for fc1 only): Y[v][n] = A[v][:]*W[n][:]+b.
// ---------------------------------------------------------------------------
template<int CIRB, int KP, int CO, int BN>
__global__ __launch_bounds__(256)
void conv_k(const char* __restrict__ A0, const char* __restrict__ Wb,
            const float* __restrict__ bias, bf16* __restrict__ Y,
            float* __restrict__ part)
{
    constexpr int NSTEP = KP / 64;
    constexpr int NF = BN / 16;
    constexpr int BI = BN / 8;
    __shared__ __align__(16) char smem[16384 + BN * 128];
    char* As = smem;
    char* Bs = smem + 16384;

    const int tid = threadIdx.x;
    const int lane = tid & 63, wid = tid >> 6, l16 = lane & 15, lhi = lane >> 4;
    const int gm = blockIdx.x;
    const int v0 = gm * 128;

    f4 acc[2][NF];
#pragma unroll
    for (int nf = 0; nf < NF; ++nf) {
        float bb = bias[nf * 16 + l16];
        f4 t = {bb, bb, bb, bb};
        acc[0][nf] = t; acc[1][nf] = t;
    }

    for (int s = 0; s < NSTEP; ++s) {
        for (int i = wid; i < BI; i += 4) {
            int o = i * 8 + (lane >> 3);
            glds16(Wb + (size_t)o * (KP * 2) + s * 128 + (((lane & 7) ^ (o & 7)) << 4),
                   Bs + i * 1024);
        }
        for (int i = wid; i < 16; i += 4) {
            int r = i * 8 + (lane >> 3);
            glds16(A0 + (size_t)(v0 + r) * CIRB + s * 128 + (((lane & 7) ^ (r & 7)) << 4),
                   As + i * 1024);
        }
        __syncthreads();
#pragma unroll
        for (int ks = 0; ks < 2; ++ks) {
            int kg = ks * 4 + lhi;
            short8 av[2];
#pragma unroll
            for (int mf = 0; mf < 2; ++mf) {
                int v = wid * 32 + mf * 16 + l16;
                av[mf] = *(const short8*)(As + v * 128 + ((kg ^ (v & 7)) << 4));
            }
#pragma unroll
            for (int nf = 0; nf < NF; ++nf) {
                int o = nf * 16 + l16;
                short8 bv = *(const short8*)(Bs + o * 128 + ((kg ^ (o & 7)) << 4));
                acc[0][nf] = __builtin_amdgcn_mfma_f32_16x16x32_bf16(av[0], bv, acc[0][nf], 0, 0, 0);
                acc[1][nf] = __builtin_amdgcn_mfma_f32_16x16x32_bf16(av[1], bv, acc[1][nf], 0, 0, 0);
            }
        }
        __syncthreads();
    }

#pragma unroll
    for (int mf = 0; mf < 2; ++mf) {
        int vb = v0 + wid * 32 + mf * 16 + lhi * 4;
#pragma unroll
        for (int nf = 0; nf < NF; ++nf) {
            int n = nf * 16 + l16;
#pragma unroll
            for (int r = 0; r < 4; ++r) {
                bf16 o; *(unsigned short*)&o = f2bu(acc[mf][nf][r]);
                Y[(size_t)(vb + r) * CO + n] = o;
            }
        }
    }
    float* ps = (float*)smem;
#pragma unroll
    for (int nf = 0; nf < NF; ++nf) {
        float sm = 0.f, sq = 0.f;
#pragma unroll
        for (int mf = 0; mf < 2; ++mf)
#pragma unroll
            for (int r = 0; r < 4; ++r) {
                float v = acc[mf][nf][r];
                sm += v; sq += v * v;
            }
        sm += __shfl_xor(sm, 16); sq += __shfl_xor(sq, 16);
        sm += __shfl_xor(sm, 32); sq += __shfl_xor(sq, 32);
        if (lane < 16) {
            ps[(wid * 2 + 0) * BN + nf * 16 + lane] = sm;
            ps[(wid * 2 + 1) * BN + nf * 16 + lane] = sq;
        }
    }
    __syncthreads();
    if (tid < BN) {
        float sm = ps[0 * BN + tid] + ps[2 * BN + tid] + ps[4 * BN + tid] + ps[6 * BN + tid];
        float sq = ps[1 * BN + tid] + ps[3 * BN + tid] + ps[5 * BN + tid] + ps[7 * BN + tid];
        float* pb = part + (size_t)(gm & 63) * 2 * BN;
        atomicAdd(&pb[tid], sm);
        atomicAdd(&pb[BN + tid], sq);
    }
}

// ---------------------------------------------------------------------------
// hx fragment loader: per-thread MFMA B-fragment of the concat input
// [y1-affine(c1) | xj-plain], K=192. v = voxel row, k8 = 16B chunk (0..23).
// ---------------------------------------------------------------------------
DEV short8 load_hx(const char* __restrict__ y1, const char* __restrict__ xj,
                   const float* __restrict__ cA, const float* __restrict__ cB,
                   size_t v, int k8)
{
    if (k8 < 12) {
        short8 raw = *(const short8*)(y1 + v * 192 + k8 * 16);
        int cb = k8 * 8;
        f4 a0 = *(const f4*)(cA + cb), a1 = *(const f4*)(cA + cb + 4);
        f4 d0 = *(const f4*)(cB + cb), d1 = *(const f4*)(cB + cb + 4);
        short8 hh;
#pragma unroll
        for (int e = 0; e < 4; ++e) {
            hh[e]     = (short)f2bu(fmaf(a0[e], bu2f((unsigned short)raw[e]),     d0[e]));
            hh[e + 4] = (short)f2bu(fmaf(a1[e], bu2f((unsigned short)raw[e + 4]), d1[e]));
        }
        return hh;
    }
    return *(const short8*)(xj + v * 192 + (k8 - 12) * 16);
}

// ---------------------------------------------------------------------------
// g_stats_k: yg = conv_g(hx)+b_g computed in regs (swapped GEMM, discarded),
// per-(b,c) InstanceNorm partials only. 64 voxels/block, 4096 blocks.
// LDS: W1c 24KB + ps 6KB -> 5 blocks/CU.
// ---------------------------------------------------------------------------
__global__ __launch_bounds__(256)
void g_stats_k(const char* __restrict__ y1, const char* __restrict__ xj,
               const float* __restrict__ c1A, const float* __restrict__ c1B,
               const float* __restrict__ biasg, const char* __restrict__ Wg,
               float* __restrict__ part)
{
    __shared__ __align__(16) char W1c[24 * 64 * 16];   // [u24][o64] 24576
    __shared__ float ps[4 * 2 * 192];                  // 6144

    const int tid = threadIdx.x;
    const int lane = tid & 63, wid = tid >> 6, l16 = lane & 15, lhi = lane >> 4;
    const int gm = blockIdx.x;
    const int v0 = gm * 64;

    short8 hfr[6];
#pragma unroll
    for (int ks = 0; ks < 6; ++ks)
        hfr[ks] = load_hx(y1, xj, c1A, c1B, (size_t)(v0 + wid * 16 + l16), ks * 4 + lhi);

    for (int nc = 0; nc < 3; ++nc) {
        for (int i = tid; i < 1536; i += 256) {
            int u = i >> 6, o = i & 63;
            glds16(Wg + (size_t)(nc * 64 + o) * 384 + (u << 4), W1c + (size_t)i * 16);
        }
        __syncthreads();
        f4 z[4];
#pragma unroll
        for (int mt = 0; mt < 4; ++mt)
            z[mt] = *(const f4*)(biasg + nc * 64 + mt * 16 + lhi * 4);
#pragma unroll
        for (int ks = 0; ks < 6; ++ks) {
            int kg = ks * 4 + lhi;
#pragma unroll
            for (int mt = 0; mt < 4; ++mt) {
                short8 wv = *(const short8*)(W1c + ((size_t)kg * 64 + mt * 16 + l16) * 16);
                z[mt] = __builtin_amdgcn_mfma_f32_16x16x32_bf16(wv, hfr[ks], z[mt], 0, 0, 0);
            }
        }
        // reduce over voxels (cols = l16 lanes)
#pragma unroll
        for (int mt = 0; mt < 4; ++mt) {
            f4 sv, qv;
#pragma unroll
            for (int r = 0; r < 4; ++r) {
                float sm = z[mt][r], sq = sm * sm;
                sm += __shfl_xor(sm, 1); sq += __shfl_xor(sq, 1);
                sm += __shfl_xor(sm, 2); sq += __shfl_xor(sq, 2);
                sm += __shfl_xor(sm, 4); sq += __shfl_xor(sq, 4);
                sm += __shfl_xor(sm, 8); sq += __shfl_xor(sq, 8);
                sv[r] = sm; qv[r] = sq;
            }
            if (l16 == 0) {
                int ch = nc * 64 + mt * 16 + lhi * 4;
                *(f4*)&ps[(wid * 2 + 0) * 192 + ch] = sv;
                *(f4*)&ps[(wid * 2 + 1) * 192 + ch] = qv;
            }
        }
        __syncthreads();
    }
    if (tid < 192) {
        float sm = ps[0 * 192 + tid] + ps[2 * 192 + tid] + ps[4 * 192 + tid] + ps[6 * 192 + tid];
        float sq = ps[1 * 192 + tid] + ps[3 * 192 + tid] + ps[5 * 192 + tid] + ps[7 * 192 + tid];
        int slot = (gm >> 11) * 32 + (gm & 31);
        float* pb = part + (size_t)slot * 2 * 192;
        atomicAdd(&pb[tid], sm);
        atomicAdd(&pb[192 + tid], sq);
    }
}

// ---------------------------------------------------------------------------
// g_fused_k: fused conv_g + IN(per b,c) + lrelu + fc2 -> y2 + BN2 partials.
// 64 voxels/block, 4096 blocks. 3 chunks of 64 yg-channels through zbuf.
// LDS: W1c 24KB + W2c 12KB + zb 9KB + ps 3KB = 48KB -> 3 blocks/CU.
// ---------------------------------------------------------------------------
__global__ __launch_bounds__(256)
void g_fused_k(const char* __restrict__ y1, const char* __restrict__ xj,
               const float* __restrict__ c1A, const float* __restrict__ c1B,
               const float* __restrict__ c2A, const float* __restrict__ c2B,
               const float* __restrict__ biasg, const float* __restrict__ biasfc2,
               const char* __restrict__ Wg, const char* __restrict__ Wfc2,
               bf16* __restrict__ y2, float* __restrict__ part)
{
    __shared__ __align__(16) char W1c[24 * 64 * 16];   // [u24][o64] 24576
    __shared__ __align__(16) char W2c[96 * 8 * 16];    // [o96][u8^] 12288
    __shared__ __align__(16) char zb[64 * 144];        // 9216
    __shared__ float ps[4 * 2 * 96];                   // 3072

    const int tid = threadIdx.x;
    const int lane = tid & 63, wid = tid >> 6, l16 = lane & 15, lhi = lane >> 4;
    const int gm = blockIdx.x;
    const int v0 = gm * 64;
    const int b = gm >> 11;

    short8 hfr[6];
#pragma unroll
    for (int ks = 0; ks < 6; ++ks)
        hfr[ks] = load_hx(y1, xj, c1A, c1B, (size_t)(v0 + wid * 16 + l16), ks * 4 + lhi);

    f4 accY[6];
#pragma unroll
    for (int nf = 0; nf < 6; ++nf) {
        float bb = biasfc2[nf * 16 + l16];
        accY[nf] = f4{bb, bb, bb, bb};
    }

    for (int nc = 0; nc < 3; ++nc) {
        for (int i = tid; i < 1536; i += 256) {
            int u = i >> 6, o = i & 63;
            glds16(Wg + (size_t)(nc * 64 + o) * 384 + (u << 4), W1c + (size_t)i * 16);
        }
        for (int i = tid; i < 768; i += 256) {
            int o = i >> 3, s = i & 7;
            glds16(Wfc2 + (size_t)o * 384 + nc * 128 + ((s ^ (o & 7)) << 4),
                   W2c + (size_t)i * 16);
        }
        __syncthreads();

        // GEMM1 swapped: z rows = yg-channel, cols = voxel (l16)
        f4 z[4];
#pragma unroll
        for (int mt = 0; mt < 4; ++mt)
            z[mt] = *(const f4*)(biasg + nc * 64 + mt * 16 + lhi * 4);
#pragma unroll
        for (int ks = 0; ks < 6; ++ks) {
            int kg = ks * 4 + lhi;
#pragma unroll
            for (int mt = 0; mt < 4; ++mt) {
                short8 wv = *(const short8*)(W1c + ((size_t)kg * 64 + mt * 16 + l16) * 16);
                z[mt] = __builtin_amdgcn_mfma_f32_16x16x32_bf16(wv, hfr[ks], z[mt], 0, 0, 0);
            }
        }
        // IN affine (per b,c) + lrelu -> zbuf (wave-private rows)
#pragma unroll
        for (int mt = 0; mt < 4; ++mt) {
            int ch = b * 192 + nc * 64 + mt * 16 + lhi * 4;
            f4 a = *(const f4*)(c2A + ch);
            f4 bb = *(const f4*)(c2B + ch);
            int v = wid * 16 + l16;
            float t0 = fmaf(a[0], z[mt][0], bb[0]); t0 = fmaxf(t0, 0.2f * t0);
            float t1 = fmaf(a[1], z[mt][1], bb[1]); t1 = fmaxf(t1, 0.2f * t1);
            float t2 = fmaf(a[2], z[mt][2], bb[2]); t2 = fmaxf(t2, 0.2f * t2);
            float t3 = fmaf(a[3], z[mt][3], bb[3]); t3 = fmaxf(t3, 0.2f * t3);
            uint2v w; w[0] = cvtpk(t0, t1); w[1] = cvtpk(t2, t3);
            *(uint2v*)(zb + (size_t)v * 144 + mt * 32 + lhi * 8) = w;
        }
        asm volatile("s_waitcnt lgkmcnt(0)" ::: "memory");
        __builtin_amdgcn_sched_barrier(0);
        // GEMM2: accY += z_chunk * Wfc2_slice   (K = 64)
#pragma unroll
        for (int ks = 0; ks < 2; ++ks) {
            int kg = ks * 4 + lhi;
            short8 av = *(const short8*)(zb + (size_t)(wid * 16 + l16) * 144 + kg * 16);
#pragma unroll
            for (int nf = 0; nf < 6; ++nf) {
                int o = nf * 16 + l16;
                short8 bv = *(const short8*)(W2c + ((size_t)o * 8 + (kg ^ (o & 7))) * 16);
                accY[nf] = __builtin_amdgcn_mfma_f32_16x16x32_bf16(av, bv, accY[nf], 0, 0, 0);
            }
        }
        __syncthreads();
    }

    // y2 store (D: col=l16 -> n, row=lhi*4+r -> voxel) + BN2 stats
    const int vb = v0 + wid * 16 + lhi * 4;
#pragma unroll
    for (int nf = 0; nf < 6; ++nf) {
        int n = nf * 16 + l16;
#pragma unroll
        for (int r = 0; r < 4; ++r) {
            bf16 o; *(unsigned short*)&o = f2bu(accY[nf][r]);
            y2[(size_t)(vb + r) * 96 + n] = o;
        }
    }
#pragma unroll
    for (int nf = 0; nf < 6; ++nf) {
        float sm = 0.f, sq = 0.f;
#pragma unroll
        for (int r = 0; r < 4; ++r) {
            float v = accY[nf][r];
            sm += v; sq += v * v;
        }
        sm += __shfl_xor(sm, 16); sq += __shfl_xor(sq, 16);
        sm += __shfl_xor(sm, 32); sq += __shfl_xor(sq, 32);
        if (lane < 16) {
            ps[(wid * 2 + 0) * 96 + nf * 16 + lane] = sm;
            ps[(wid * 2 + 1) * 96 + nf * 16 + lane] = sq;
        }
    }
    __syncthreads();
    if (tid < 96) {
        float sm = ps[0 * 96 + tid] + ps[2 * 96 + tid] + ps[4 * 96 + tid] + ps[6 * 96 + tid];
        float sq = ps[1 * 96 + tid] + ps[3 * 96 + tid] + ps[5 * 96 + tid] + ps[7 * 96 + tid];
        float* pb = part + (size_t)(gm & 63) * 2 * 96;
        atomicAdd(&pb[tid], sm);
        atomicAdd(&pb[96 + tid], sq);
    }
}

// ---------------------------------------------------------------------------
// ffn_stats_k (r9): x2 = A3*y2+B3+xT per-fragment in regs, write global,
// then 4 stats-only GEMM quarters vs W1.
// ---------------------------------------------------------------------------
__global__ __launch_bounds__(256)
void ffn_stats_k(const char* __restrict__ y2, const char* __restrict__ xT,
                 const float* __restrict__ cfA, const float* __restrict__ cfB,
                 const float* __restrict__ biasf1, const char* __restrict__ Wf1,
                 char* __restrict__ x2, float* __restrict__ part)
{
    __shared__ __align__(16) char Bs[96 * 192];
    __shared__ float ps[8 * 96];

    const int tid = threadIdx.x;
    const int lane = tid & 63, wid = tid >> 6, l16 = lane & 15, lhi = lane >> 4;
    const int gm = blockIdx.x;
    const int v0 = gm * 128;

    short8 afr[2][3];
#pragma unroll
    for (int mf = 0; mf < 2; ++mf)
#pragma unroll
        for (int ks = 0; ks < 3; ++ks) {
            int v = v0 + wid * 32 + mf * 16 + l16;
            int kg = ks * 4 + lhi, cb = kg * 8;
            short8 yv = *(const short8*)(y2 + (size_t)v * 192 + kg * 16);
            short8 xv = *(const short8*)(xT + (size_t)v * 192 + kg * 16);
            f4 a0 = *(const f4*)(cfA + cb), a1 = *(const f4*)(cfA + cb + 4);
            f4 d0 = *(const f4*)(cfB + cb), d1 = *(const f4*)(cfB + cb + 4);
            short8 o;
#pragma unroll
            for (int e = 0; e < 4; ++e) {
                float t0 = fmaf(a0[e], bu2f((unsigned short)yv[e]),     d0[e]) + bu2f((unsigned short)xv[e]);
                float t1 = fmaf(a1[e], bu2f((unsigned short)yv[e + 4]), d1[e]) + bu2f((unsigned short)xv[e + 4]);
                o[e]     = (short)f2bu(t0);
                o[e + 4] = (short)f2bu(t1);
            }
            afr[mf][ks] = o;
            *(short8*)(x2 + (size_t)v * 192 + kg * 16) = o;
        }

    for (int q = 0; q < 4; ++q) {
        for (int i = tid; i < 1152; i += 256) {
            int u = i / 96, o = i - u * 96;
            glds16(Wf1 + (size_t)(q * 96 + o) * 192 + (u << 4), Bs + (size_t)i * 16);
        }
        __syncthreads();
        f4 acc[2][6];
#pragma unroll
        for (int nf = 0; nf < 6; ++nf) {
            float bb = biasf1[q * 96 + nf * 16 + l16];
            f4 t = {bb, bb, bb, bb};
            acc[0][nf] = t; acc[1][nf] = t;
        }
#pragma unroll
        for (int ks = 0; ks < 3; ++ks) {
            int kg = ks * 4 + lhi;
#pragma unroll
            for (int nf = 0; nf < 6; ++nf) {
                int o = nf * 16 + l16;
                short8 bv = *(const short8*)(Bs + ((size_t)kg * 96 + o) * 16);
                acc[0][nf] = __builtin_amdgcn_mfma_f32_16x16x32_bf16(afr[0][ks], bv, acc[0][nf], 0, 0, 0);
                acc[1][nf] = __builtin_amdgcn_mfma_f32_16x16x32_bf16(afr[1][ks], bv, acc[1][nf], 0, 0, 0);
            }
        }
#pragma unroll
        for (int nf = 0; nf < 6; ++nf) {
            float sm = 0.f, sq = 0.f;
#pragma unroll
            for (int mf = 0; mf < 2; ++mf)
#pragma unroll
                for (int r = 0; r < 4; ++r) {
                    float v = acc[mf][nf][r];
                    sm += v; sq += v * v;
                }
            sm += __shfl_xor(sm, 16); sq += __shfl_xor(sq, 16);
            sm += __shfl_xor(sm, 32); sq += __shfl_xor(sq, 32);
            if (lane < 16) {
                ps[(wid * 2 + 0) * 96 + nf * 16 + lane] = sm;
                ps[(wid * 2 + 1) * 96 + nf * 16 + lane] = sq;
            }
        }
        __syncthreads();
        if (tid < 96) {
            float sm = ps[0 * 96 + tid] + ps[2 * 96 + tid] + ps[4 * 96 + tid] + ps[6 * 96 + tid];
            float sq = ps[1 * 96 + tid] + ps[3 * 96 + tid] + ps[5 * 96 + tid] + ps[7 * 96 + tid];
            float* pb = part + (size_t)(q * 64 + (gm & 63)) * 192;
            atomicAdd(&pb[tid], sm);
            atomicAdd(&pb[96 + tid], sq);
        }
        __syncthreads();
    }
}

// ---------------------------------------------------------------------------
// ffn_k (r9): fused f1+lrelu+BNf1+f2. x2 frags in regs; W single-buffered;
// zbuf wave-private [v][144B]. LDS 46KB.
// ---------------------------------------------------------------------------
__global__ __launch_bounds__(256)
void ffn_k(const char* __restrict__ x2, const float* __restrict__ cfA4,
           const float* __restrict__ cfB4, const float* __restrict__ biasf2,
           const char* __restrict__ Wf1, const char* __restrict__ Wf2,
           bf16* __restrict__ y4, float* __restrict__ part)
{
    __shared__ __align__(16) char W1c[12 * 64 * 16];
    __shared__ __align__(16) char W2c[8 * 96 * 16];
    __shared__ __align__(16) char zb[128 * 144];
    __shared__ float ps[8 * 96];

    const int tid = threadIdx.x;
    const int lane = tid & 63, wid = tid >> 6, l16 = lane & 15, lhi = lane >> 4;
    const int gm = blockIdx.x;
    const int v0 = gm * 128;

    short8 xfr[2][3];
#pragma unroll
    for (int nt = 0; nt < 2; ++nt)
#pragma unroll
        for (int ks = 0; ks < 3; ++ks)
            xfr[nt][ks] = *(const short8*)(x2 + (size_t)(v0 + wid * 32 + nt * 16 + l16) * 192
                                           + (ks * 4 + lhi) * 16);

    f4 accY[2][6];
#pragma unroll
    for (int nf = 0; nf < 6; ++nf) {
        float bb = biasf2[nf * 16 + l16];
        f4 t = {bb, bb, bb, bb};
        accY[0][nf] = t; accY[1][nf] = t;
    }

    for (int nc = 0; nc < 6; ++nc) {
        for (int i = tid; i < 768; i += 256) {
            int u = i / 64, o = i - u * 64;
            glds16(Wf1 + (size_t)(nc * 64 + o) * 192 + (u << 4), W1c + (size_t)i * 16);
        }
        for (int i = tid; i < 768; i += 256) {
            int u = i / 96, o = i - u * 96;
            glds16(Wf2 + (size_t)o * 768 + nc * 128 + (u << 4), W2c + (size_t)i * 16);
        }
        __syncthreads();

        f4 z[4][2];
#pragma unroll
        for (int mt = 0; mt < 4; ++mt) { z[mt][0] = f4{0,0,0,0}; z[mt][1] = f4{0,0,0,0}; }
#pragma unroll
        for (int ks = 0; ks < 3; ++ks) {
            int kg = ks * 4 + lhi;
#pragma unroll
            for (int mt = 0; mt < 4; ++mt) {
                int o = mt * 16 + l16;
                short8 wv = *(const short8*)(W1c + ((size_t)kg * 64 + o) * 16);
                z[mt][0] = __builtin_amdgcn_mfma_f32_16x16x32_bf16(wv, xfr[0][ks], z[mt][0], 0, 0, 0);
                z[mt][1] = __builtin_amdgcn_mfma_f32_16x16x32_bf16(wv, xfr[1][ks], z[mt][1], 0, 0, 0);
            }
        }
#pragma unroll
        for (int mt = 0; mt < 4; ++mt) {
            int ch = nc * 64 + mt * 16 + lhi * 4;
            f4 a = *(const f4*)(cfA4 + ch);
            f4 bb = *(const f4*)(cfB4 + ch);
#pragma unroll
            for (int nt = 0; nt < 2; ++nt) {
                int v = wid * 32 + nt * 16 + l16;
                float t0 = fmaf(a[0], z[mt][nt][0], bb[0]); t0 = fmaxf(t0, 0.2f * t0);
                float t1 = fmaf(a[1], z[mt][nt][1], bb[1]); t1 = fmaxf(t1, 0.2f * t1);
                float t2 = fmaf(a[2], z[mt][nt][2], bb[2]); t2 = fmaxf(t2, 0.2f * t2);
                float t3 = fmaf(a[3], z[mt][nt][3], bb[3]); t3 = fmaxf(t3, 0.2f * t3);
                uint2v w; w[0] = cvtpk(t0, t1); w[1] = cvtpk(t2, t3);
                *(uint2v*)(zb + (size_t)v * 144 + mt * 32 + lhi * 8) = w;
            }
        }
        asm volatile("s_waitcnt lgkmcnt(0)" ::: "memory");
        __builtin_amdgcn_sched_barrier(0);
#pragma unroll
        for (int ks = 0; ks < 2; ++ks) {
            int kg = ks * 4 + lhi;
            short8 av[2];
#pragma unroll
            for (int mf = 0; mf < 2; ++mf)
                av[mf] = *(const short8*)(zb + (size_t)(wid * 32 + mf * 16 + l16) * 144 + kg * 16);
#pragma unroll
            for (int nf = 0; nf < 6; ++nf) {
                int o = nf * 16 + l16;
                short8 bv = *(const short8*)(W2c + ((size_t)kg * 96 + o) * 16);
                accY[0][nf] = __builtin_amdgcn_mfma_f32_16x16x32_bf16(av[0], bv, accY[0][nf], 0, 0, 0);
                accY[1][nf] = __builtin_amdgcn_mfma_f32_16x16x32_bf16(av[1], bv, accY[1][nf], 0, 0, 0);
            }
        }
        __syncthreads();
    }

#pragma unroll
    for (int mf = 0; mf < 2; ++mf) {
        int vb = v0 + wid * 32 + mf * 16 + lhi * 4;
#pragma unroll
        for (int nf = 0; nf < 6; ++nf) {
            int n = nf * 16 + l16;
#pragma unroll
            for (int r = 0; r < 4; ++r) {
                bf16 o; *(unsigned short*)&o = f2bu(accY[mf][nf][r]);
                y4[(size_t)(vb + r) * 96 + n] = o;
            }
        }
    }
#pragma unroll
    for (int nf = 0; nf < 6; ++nf) {
        float sm = 0.f, sq = 0.f;
#pragma unroll
        for (int mf = 0; mf < 2; ++mf)
#pragma unroll
            for (int r = 0; r < 4; ++r) {
                float v = accY[mf][nf][r];
                sm += v; sq += v * v;
            }
        sm += __shfl_xor(sm, 16); sq += __shfl_xor(sq, 16);
        sm += __shfl_xor(sm, 32); sq += __shfl_xor(sq, 32);
        if (lane < 16) {
            ps[(wid * 2 + 0) * 96 + nf * 16 + lane] = sm;
            ps[(wid * 2 + 1) * 96 + nf * 16 + lane] = sq;
        }
    }
    __syncthreads();
    if (tid < 96) {
        float sm = ps[0 * 96 + tid] + ps[2 * 96 + tid] + ps[4 * 96 + tid] + ps[6 * 96 + tid];
        float sq = ps[1 * 96 + tid] + ps[3 * 96 + tid] + ps[5 * 96 + tid] + ps[7 * 96 + tid];
        float* pb = part + (size_t)(gm & 63) * 192;
        atomicAdd(&pb[tid], sm);
        atomicAdd(&pb[96 + tid], sq);
    }
}

// ---------------------------------------------------------------------------
// partial sums -> affine coefs  A = g*rsqrt(var+eps), B = be - m*A (+ A*bias)
// ---------------------------------------------------------------------------
__global__ void finalize_k(const float* __restrict__ part, float* __restrict__ cf,
                           const float* __restrict__ g, const float* __restrict__ be,
                           const float* __restrict__ bias,
                           int nStats, int CO, int BN, int perB, float invN)
{
    int s = blockIdx.x * 64 + threadIdx.x;
    if (s >= nStats) return;
    int ch = perB ? (s % CO) : s;
    int bb = perB ? (s / CO) : 0;
    int gy = ch / BN, c = ch - gy * BN;
    int j0 = perB ? bb * 32 : 0, cnt = perB ? 32 : 64;
    float sm = 0.f, sq = 0.f;
    for (int j = 0; j < cnt; ++j) {
        const float* pb = part + (size_t)(gy * 64 + j0 + j) * 2 * BN;
        sm += pb[c]; sq += pb[BN + c];
    }
    float m = sm * invN;
    float var = fmaf(-m, m, sq * invN);
    float A = g[ch] * rsqrtf(var + 1e-5f);
    cf[s] = A;
    float B = fmaf(-m, A, be[ch]);
    if (bias) B = fmaf(A, bias[ch], B);
    cf[1024 + s] = B;
}

// ---------------------------------------------------------------------------
// weight prep: f32 [CO][CI] -> bf16 [CO][KP]
// ---------------------------------------------------------------------------
__global__ void wprep_k(const float* __restrict__ w0, const float* __restrict__ w1,
                        const float* __restrict__ w2, const float* __restrict__ w3,
                        const float* __restrict__ w4, bf16* __restrict__ Wb)
{
    int i = blockIdx.x * 256 + threadIdx.x;     // < 141312
    if (i >= 141312) return;
    const float* src; int r, KP, CI, off;
    if (i < 12288)       { src = w0; r = i;          KP = 128; CI = 96;  off = 0; }
    else if (i < 49152)  { src = w1; r = i - 12288;  KP = 192; CI = 192; off = 12288; }
    else if (i < 67584)  { src = w2; r = i - 49152;  KP = 192; CI = 192; off = 49152; }
    else if (i < 104448) { src = w3; r = i - 67584;  KP = 96;  CI = 96;  off = 67584; }
    else                 { src = w4; r = i - 104448; KP = 384; CI = 384; off = 104448; }
    int o = r / KP, k = r - o * KP;
    float v = (k < CI) ? src[o * CI + k] : 0.f;
    bf16 h; *(unsigned short*)&h = f2bu(v);
    Wb[off + r] = h;
}

// ---------------------------------------------------------------------------
// tin: x f32 [b][c][s] -> xT bf16 [v][96] via LDS transpose
// ---------------------------------------------------------------------------
__global__ __launch_bounds__(256)
void tin_k(const float* __restrict__ x, char* __restrict__ xT)
{
    __shared__ float ldsT[128 * 97];
    const int gm = blockIdx.x, b = gm >> 10, s0 = (gm & 1023) * 128;
    const int t = threadIdx.x;
#pragma unroll
    for (int i = 0; i < 12; ++i) {
        int idx = t + 256 * i;
        int c = idx >> 5, s4 = idx & 31;
        f4 r = *(const f4*)(x + ((size_t)(b * 96 + c) << 17) + s0 + s4 * 4);
#pragma unroll
        for (int j = 0; j < 4; ++j) ldsT[(s4 * 4 + j) * 97 + c] = r[j];
    }
    __syncthreads();
#pragma unroll
    for (int i = 0; i < 6; ++i) {
        int idx = t + 256 * i;
        int r = idx / 12, uc = idx % 12, cb = uc * 8;
        short8 o;
#pragma unroll
        for (int e = 0; e < 8; ++e) o[e] = (short)f2bu(ldsT[r * 97 + cb + e]);
        *(short8*)(xT + (size_t)(b * Sq + s0 + r) * 192 + uc * 16) = o;
    }
}

// ---------------------------------------------------------------------------
// MR pass 1a: dminp[b][h][w][dh][p][c] = raw min over d in half dh, parity p
// ---------------------------------------------------------------------------
__global__ __launch_bounds__(192)
void mr_dmin_k(const char* __restrict__ y1, char* __restrict__ dminp)
{
    const int wq = blockIdx.x >> 1, dh = blockIdx.x & 1;
    const int h = blockIdx.y, b = blockIdx.z;
    const int t = threadIdx.x;
    const int w = wq * 16 + t / 12, uc = t % 12;
    const char* base = y1 + (size_t)(b * Sq + dh * 16 * 4096 + h * 64 + w) * 192 + uc * 16;
    float mn[2][8];
#pragma unroll
    for (int p = 0; p < 2; ++p)
#pragma unroll
        for (int e = 0; e < 8; ++e) mn[p][e] = 1e30f;
#pragma unroll 4
    for (int i = 0; i < 16; ++i) {
        short8 raw = *(const short8*)(base + (size_t)i * (4096 * 192));
        int p = i & 1;
#pragma unroll
        for (int e = 0; e < 8; ++e)
            mn[p][e] = fminf(mn[p][e], bu2f((unsigned short)raw[e]));
    }
#pragma unroll
    for (int p = 0; p < 2; ++p) {
        short8 o;
#pragma unroll
        for (int e = 0; e < 8; ++e) o[e] = (short)f2bu(mn[p][e]);
        *(short8*)(dminp + (size_t)((((b * 64 + h) * 64 + w) * 2 + dh) * 2 + p) * 192 + uc * 16) = o;
    }
}

// ---------------------------------------------------------------------------
// MR pass 1b: hminp[b][d][w][hq][p][c] = raw min over h in quarter hq, parity p
// ---------------------------------------------------------------------------
__global__ __launch_bounds__(192)
void mr_hmin_k(const char* __restrict__ y1, char* __restrict__ hminp)
{
    const int wq = blockIdx.x >> 2, hq = blockIdx.x & 3;
    const int d = blockIdx.y, b = blockIdx.z;
    const int t = threadIdx.x;
    const int w = wq * 16 + t / 12, uc = t % 12;
    const char* base = y1 + (size_t)(b * Sq + d * 4096 + hq * 16 * 64 + w) * 192 + uc * 16;
    float mn[2][8];
#pragma unroll
    for (int p = 0; p < 2; ++p)
#pragma unroll
        for (int e = 0; e < 8; ++e) mn[p][e] = 1e30f;
#pragma unroll 4
    for (int i = 0; i < 16; ++i) {
        short8 raw = *(const short8*)(base + (size_t)i * (64 * 192));
        int p = i & 1;
#pragma unroll
        for (int e = 0; e < 8; ++e)
            mn[p][e] = fminf(mn[p][e], bu2f((unsigned short)raw[e]));
    }
#pragma unroll
    for (int p = 0; p < 2; ++p) {
        short8 o;
#pragma unroll
        for (int e = 0; e < 8; ++e) o[e] = (short)f2bu(mn[p][e]);
        *(short8*)(hminp + (size_t)((((b * 32 + d) * 64 + w) * 4 + hq) * 2 + p) * 192 + uc * 16) = o;
    }
}

// ---------------------------------------------------------------------------
// MR pass 2: xj = A_c * (y1 - min(dminp x2, hminp x4, wmin))
// ---------------------------------------------------------------------------
__global__ __launch_bounds__(256)
void mr_p2_k(const char* __restrict__ y1, const float* __restrict__ cfA,
             const char* __restrict__ dminp, const char* __restrict__ hminp,
             char* __restrict__ xj)
{
    __shared__ __align__(16) char rowb[64 * 96 * 2];
    __shared__ float wlds[2 * 96];
    const int h = blockIdx.x, d = blockIdx.y, b = blockIdx.z;
    const int t = threadIdx.x;

    short8 hv[3];
#pragma unroll
    for (int j = 0; j < 3; ++j) {
        int slot = t + 256 * j;
        int w = slot / 12, uc = slot % 12;
        short8 raw = *(const short8*)(y1 + (size_t)(b * Sq + d * 4096 + h * 64 + w) * 192 + uc * 16);
        hv[j] = raw;
        *(short8*)(rowb + slot * 16) = raw;
    }
    __syncthreads();
    if (t < 192) {
        int p = t / 96, c = t % 96;
        float m = 1e30f;
        for (int w2 = p; w2 < 64; w2 += 2)
            m = fminf(m, bu2f(*(const unsigned short*)(rowb + (w2 * 96 + c) * 2)));
        wlds[t] = m;
    }
    __syncthreads();
#pragma unroll
    for (int j = 0; j < 3; ++j) {
        int slot = t + 256 * j;
        int w = slot / 12, uc = slot % 12, cb = uc * 8;
        const char* dp = dminp + (size_t)((((b * 64 + h) * 64 + w) * 2) * 2 + (d & 1)) * 192 + uc * 16;
        short8 dm0 = *(const short8*)(dp);
        short8 dm1 = *(const short8*)(dp + 384);
        const char* hp = hminp + (size_t)((((b * 32 + d) * 64 + w) * 4) * 2 + (h & 1)) * 192 + uc * 16;
        short8 hm0 = *(const short8*)(hp);
        short8 hm1 = *(const short8*)(hp + 384);
        short8 hm2 = *(const short8*)(hp + 768);
        short8 hm3 = *(const short8*)(hp + 1152);
        f4 a0 = *(const f4*)(cfA + cb), a1 = *(const f4*)(cfA + cb + 4);
        short8 xo;
#pragma unroll
        for (int e = 0; e < 8; ++e) {
            float m = fminf(
                fminf(bu2f((unsigned short)dm0[e]), bu2f((unsigned short)dm1[e])),
                fminf(fminf(fminf(bu2f((unsigned short)hm0[e]), bu2f((unsigned short)hm1[e])),
                            fminf(bu2f((unsigned short)hm2[e]), bu2f((unsigned short)hm3[e]))),
                      wlds[(w & 1) * 96 + cb + e]));
            float A = (e < 4) ? a0[e] : a1[e - 4];
            xo[e] = (short)f2bu(A * (bu2f((unsigned short)hv[j][e]) - m));
        }
        *(short8*)(xj + (size_t)(b * Sq + d * 4096 + h * 64 + w) * 192 + uc * 16) = xo;
    }
}

// ---------------------------------------------------------------------------
// tout: out f32 [b][c][s] = A5*y4 + B5 + x2   (transpose via LDS)
// ---------------------------------------------------------------------------
__global__ __launch_bounds__(256)
void tout_k(const char* __restrict__ y4, const float* __restrict__ cfA,
            const float* __restrict__ cfB, const char* __restrict__ x2,
            float* __restrict__ outp)
{
    __shared__ float ldsT[128 * 97];
    const int gm = blockIdx.x, b = gm >> 10, s0 = (gm & 1023) * 128;
    const int t = threadIdx.x;
#pragma unroll
    for (int i = 0; i < 6; ++i) {
        int idx = t + 256 * i;
        int r = idx / 12, uc = idx % 12, cb = uc * 8;
        size_t vv = (size_t)(b * Sq + s0 + r);
        short8 yv = *(const short8*)(y4 + vv * 192 + uc * 16);
        short8 xv = *(const short8*)(x2 + vv * 192 + uc * 16);
        f4 a0 = *(const f4*)(cfA + cb), a1 = *(const f4*)(cfA + cb + 4);
        f4 d0 = *(const f4*)(cfB + cb), d1 = *(const f4*)(cfB + cb + 4);
#pragma unroll
        for (int e = 0; e < 4; ++e) {
            ldsT[r * 97 + cb + e]     = fmaf(a0[e], bu2f((unsigned short)yv[e]),     d0[e]) + bu2f((unsigned short)xv[e]);
            ldsT[r * 97 + cb + e + 4] = fmaf(a1[e], bu2f((unsigned short)yv[e + 4]), d1[e]) + bu2f((unsigned short)xv[e + 4]);
        }
    }
    __syncthreads();
#pragma unroll
    for (int i = 0; i < 12; ++i) {
        int idx = t + 256 * i;
        int c = idx >> 5, s4 = idx & 31;
        f4 o;
#pragma unroll
        for (int j = 0; j < 4; ++j) o[j] = ldsT[(s4 * 4 + j) * 97 + c];
        *(f4*)(outp + ((size_t)(b * 96 + c) << 17) + s0 + s4 * 4) = o;
    }
}

// ===========================================================================
extern "C" void kernel_launch(void* const* d_in, const int* in_sizes, int n_in,
                              void* d_out, int out_size, void* d_ws, size_t ws_size,
                              hipStream_t stream)
{
    (void)in_sizes; (void)n_in; (void)out_size; (void)ws_size;

    const float* x      = (const float*)d_in[0];
    const float* w_fc1  = (const float*)d_in[1];
    const float* b_fc1  = (const float*)d_in[2];
    const float* g_bn1  = (const float*)d_in[3];
    const float* be_bn1 = (const float*)d_in[4];
    const float* w_g    = (const float*)d_in[5];
    const float* b_g    = (const float*)d_in[6];
    const float* g_in   = (const float*)d_in[7];
    const float* be_in  = (const float*)d_in[8];
    const float* w_fc2  = (const float*)d_in[9];
    const float* b_fc2  = (const float*)d_in[10];
    const float* g_bn2  = (const float*)d_in[11];
    const float* be_bn2 = (const float*)d_in[12];
    const float* w_f1   = (const float*)d_in[13];
    const float* b_f1   = (const float*)d_in[14];
    const float* g_bnf1 = (const float*)d_in[15];
    const float* be_bnf1= (const float*)d_in[16];
    const float* w_f2   = (const float*)d_in[17];
    const float* b_f2   = (const float*)d_in[18];
    const float* g_bnf2 = (const float*)d_in[19];
    const float* be_bnf2= (const float*)d_in[20];
    float* outp = (float*)d_out;

    char* W = (char*)d_ws;
    char* xT    = W;
    char* y1    = W + 50331648ull;
    char* dminp = W + 100663296ull;
    char* hminp = W + 113246208ull;
    char* xj    = W + 125829120ull;
    char* y2    = W + 176160768ull;    // old yg slot (y1 stays live for g_fused)
    char* y4    = W + 201326592ull;
    char* x2    = W + 251658240ull;
    char* M     = W + 301989888ull;
    bf16*  Wb   = (bf16*)M;               // 282624 B
    float* cf   = (float*)(M + 307200);   // 5 slots x 2048 f32
    float* part = (float*)(M + 348160);   // 5 slots x 49152 f32

    hipMemsetAsync(part, 0, 5 * 196608, stream);

    const float invBN = 1.f / (float)NVq, invIN = 1.f / (float)Sq;
    dim3 blk(256);
    float* c1 = cf, *c2 = cf + 2048, *c3 = cf + 4096, *c4 = cf + 6144, *c5 = cf + 8192;
    const char* Wfc1 = (const char*)Wb;
    const char* Wg   = (const char*)Wb + 24576;
    const char* Wfc2 = (const char*)Wb + 98304;
    const char* Wf1  = (const char*)Wb + 135168;
    const char* Wf2  = (const char*)Wb + 208896;

    wprep_k<<<552, blk, 0, stream>>>(w_fc1, w_g, w_fc2, w_f1, w_f2, Wb);
    tin_k<<<2048, blk, 0, stream>>>(x, xT);

    // fc1: 96 -> 96 (plain, gload_lds)
    conv_k<192, 128, 96, 96><<<2048, blk, 0, stream>>>(
        xT, Wfc1, b_fc1, (bf16*)y1, part);
    finalize_k<<<2, 64, 0, stream>>>(part, c1, g_bn1, be_bn1, nullptr, 96, 96, 96, 0, invBN);

    // MRConv on raw y1 (A>0): partial mins, then xj = A*(y1 - min3)
    mr_dmin_k<<<dim3(8, 64, 2), dim3(192), 0, stream>>>(y1, dminp);
    mr_hmin_k<<<dim3(16, 32, 2), dim3(192), 0, stream>>>(y1, hminp);
    mr_p2_k<<<dim3(64, 32, 2), blk, 0, stream>>>(y1, c1, dminp, hminp, xj);

    // Grapher: stats-only pass (IN per b,c), then fused convg+IN+lrelu+fc2
    g_stats_k<<<4096, blk, 0, stream>>>(y1, xj, c1, c1 + 1024, b_g, Wg, part + 49152);
    finalize_k<<<6, 64, 0, stream>>>(part + 49152, c2, g_in, be_in, nullptr, 384, 192, 192, 1, invIN);

    g_fused_k<<<4096, blk, 0, stream>>>(y1, xj, c1, c1 + 1024, c2, c2 + 1024,
                                        b_g, b_fc2, Wg, Wfc2, (bf16*)y2, part + 98304);
    finalize_k<<<2, 64, 0, stream>>>(part + 98304, c3, g_bn2, be_bn2, nullptr, 96, 96, 96, 0, invBN);

    // FFN phase 1: x2 = A3*y2+B3+xT (write) + f1 stats-only -> BNf1 partials
    ffn_stats_k<<<2048, blk, 0, stream>>>(y2, xT, c3, c3 + 1024, b_f1, Wf1, x2, part + 147456);
    finalize_k<<<6, 64, 0, stream>>>(part + 147456, c4, g_bnf1, be_bnf1, b_f1, 384, 384, 96, 0, invBN);

    // FFN phase 2: fused f1+lrelu+f2 -> y4 + BNf2 partials
    ffn_k<<<2048, blk, 0, stream>>>(x2, c4, c4 + 1024, b_f2, Wf1, Wf2, (bf16*)y4, part + 196608);
    finalize_k<<<2, 64, 0, stream>>>(part + 196608, c5, g_bnf2, be_bnf2, nullptr, 96, 96, 96, 0, invBN);

    tout_k<<<2048, blk, 0, stream>>>(y4, c5, c5 + 1024, x2, outp);
}

// Round 12
// 451.105 us; speedup vs baseline: 1.2335x; 1.1887x over previous
//
#include <hip/hip_runtime.h>
#include <hip/hip_bf16.h>

// ============================================================================
// NexToU encoder block, MFMA bf16, [voxel][channel] layout. Round 12:
// VERBATIM restore of round-6 (best measured: 451.95us).
//   staged convs (fc1/conv_g/fc2) @3.3TB/s, MR 3-pass, ffn_stats (ewx2+f1
//   stats fused), ffn_k (fused f1+lrelu+f2, y3 never in HBM), tin/tout.
// Rounds 7-11 established this as the practical plateau: all occupancy /
// barrier / W-source / fusion variants regressed or were neutral.
// ============================================================================

typedef __hip_bfloat16 bf16;
typedef __attribute__((ext_vector_type(8))) short short8;
typedef __attribute__((ext_vector_type(4))) float f4;
typedef __attribute__((ext_vector_type(4))) unsigned short us4;

#define DEV static __device__ __forceinline__

constexpr int Sq  = 131072;   // D*H*W
constexpr int NVq = 262144;   // B*S

DEV float bu2f(unsigned short u) { return __uint_as_float(((unsigned)u) << 16); }
DEV unsigned short f2bu(float f) {
    unsigned i = __float_as_uint(f);
    unsigned r = i + 0x7FFFu + ((i >> 16) & 1u);   // RNE (finite inputs only)
    return (unsigned short)(r >> 16);
}
DEV void glds16(const void* g, void* l) {
    __builtin_amdgcn_global_load_lds(
        (const __attribute__((address_space(1))) unsigned*)g,
        (__attribute__((address_space(3))) unsigned*)l, 16, 0, 0);
}

// ---------------------------------------------------------------------------
// MFMA conv (round-6 proven): Y[v][n] = sum_k A[v][k]*W[n][k] + bias, stats.
// AMODE: 0 plain gload_lds; 2 per-(b,c) affine+lrelu (fc2);
//        4 dual-stream concat (y1-affine | xj-plain) for conv g.
// LDS: chunk u of row v at unit u^(v&7) -> conflict-free ds_read_b128.
// ---------------------------------------------------------------------------
template<int CIRB, int KP, int CO, int BN, int AMODE, bool PERB>
__global__ __launch_bounds__(256)
void conv_k(const char* __restrict__ A0, const char* __restrict__ A1,
            const char* __restrict__ Wb, const float* __restrict__ bias,
            const float* __restrict__ cfA, const float* __restrict__ cfB,
            bf16* __restrict__ Y, float* __restrict__ part)
{
    constexpr int NSTEP = KP / 64;
    constexpr int NF = BN / 16;
    constexpr int BI = BN / 8;
    __shared__ __align__(16) char smem[16384 + BN * 128];
    char* As = smem;
    char* Bs = smem + 16384;

    const int tid = threadIdx.x;
    const int lane = tid & 63, wid = tid >> 6, l16 = lane & 15, lhi = lane >> 4;
    const int gm = blockIdx.x, gy = blockIdx.y;
    const int v0 = gm * 128;
    const int b = gm >> 10;
    const int n0g = gy * BN;

    f4 acc[2][NF];
#pragma unroll
    for (int nf = 0; nf < NF; ++nf) {
        float bb = bias[n0g + nf * 16 + l16];
        f4 t = {bb, bb, bb, bb};
        acc[0][nf] = t; acc[1][nf] = t;
    }

    for (int s = 0; s < NSTEP; ++s) {
        for (int i = wid; i < BI; i += 4) {
            int o = i * 8 + (lane >> 3);
            glds16(Wb + (size_t)(n0g + o) * (KP * 2) + s * 128 + (((lane & 7) ^ (o & 7)) << 4),
                   Bs + i * 1024);
        }
        if constexpr (AMODE == 0) {
            for (int i = wid; i < 16; i += 4) {
                int r = i * 8 + (lane >> 3);
                glds16(A0 + (size_t)(v0 + r) * CIRB + s * 128 + (((lane & 7) ^ (r & 7)) << 4),
                       As + i * 1024);
            }
        } else {
#pragma unroll
            for (int j = 0; j < 4; ++j) {
                int idx = tid + 256 * j;
                int v = idx >> 3, u = idx & 7;
                int k8 = s * 8 + u;
                short8 hh;
                if constexpr (AMODE == 2) {        // fc2: per-(b,c) affine+lrelu
                    short8 raw = *(const short8*)(A0 + (size_t)(v0 + v) * CIRB + k8 * 16);
                    int cb = b * KP + k8 * 8;
                    f4 a0 = *(const f4*)(cfA + cb), a1 = *(const f4*)(cfA + cb + 4);
                    f4 d0 = *(const f4*)(cfB + cb), d1 = *(const f4*)(cfB + cb + 4);
#pragma unroll
                    for (int e = 0; e < 4; ++e) {
                        float t0 = fmaf(a0[e], bu2f((unsigned short)raw[e]),     d0[e]);
                        float t1 = fmaf(a1[e], bu2f((unsigned short)raw[e + 4]), d1[e]);
                        t0 = fmaxf(t0, 0.2f * t0);
                        t1 = fmaxf(t1, 0.2f * t1);
                        hh[e] = (short)f2bu(t0); hh[e + 4] = (short)f2bu(t1);
                    }
                } else {                           // conv g: y1-affine | xj-plain
                    if (k8 < 12) {
                        short8 raw = *(const short8*)(A0 + (size_t)(v0 + v) * 192 + k8 * 16);
                        int cb = k8 * 8;
                        f4 a0 = *(const f4*)(cfA + cb), a1 = *(const f4*)(cfA + cb + 4);
                        f4 d0 = *(const f4*)(cfB + cb), d1 = *(const f4*)(cfB + cb + 4);
#pragma unroll
                        for (int e = 0; e < 4; ++e) {
                            hh[e]     = (short)f2bu(fmaf(a0[e], bu2f((unsigned short)raw[e]),     d0[e]));
                            hh[e + 4] = (short)f2bu(fmaf(a1[e], bu2f((unsigned short)raw[e + 4]), d1[e]));
                        }
                    } else {
                        hh = *(const short8*)(A1 + (size_t)(v0 + v) * 192 + (k8 - 12) * 16);
                    }
                }
                *(short8*)(As + v * 128 + ((u ^ (v & 7)) << 4)) = hh;
            }
        }
        __syncthreads();
#pragma unroll
        for (int ks = 0; ks < 2; ++ks) {
            int kg = ks * 4 + lhi;
            short8 av[2];
#pragma unroll
            for (int mf = 0; mf < 2; ++mf) {
                int v = wid * 32 + mf * 16 + l16;
                av[mf] = *(const short8*)(As + v * 128 + ((kg ^ (v & 7)) << 4));
            }
#pragma unroll
            for (int nf = 0; nf < NF; ++nf) {
                int o = nf * 16 + l16;
                short8 bv = *(const short8*)(Bs + o * 128 + ((kg ^ (o & 7)) << 4));
                acc[0][nf] = __builtin_amdgcn_mfma_f32_16x16x32_bf16(av[0], bv, acc[0][nf], 0, 0, 0);
                acc[1][nf] = __builtin_amdgcn_mfma_f32_16x16x32_bf16(av[1], bv, acc[1][nf], 0, 0, 0);
            }
        }
        __syncthreads();
    }

#pragma unroll
    for (int mf = 0; mf < 2; ++mf) {
        int vb = v0 + wid * 32 + mf * 16 + lhi * 4;
#pragma unroll
        for (int nf = 0; nf < NF; ++nf) {
            int n = n0g + nf * 16 + l16;
#pragma unroll
            for (int r = 0; r < 4; ++r) {
                bf16 o; *(unsigned short*)&o = f2bu(acc[mf][nf][r]);
                Y[(size_t)(vb + r) * CO + n] = o;
            }
        }
    }
    float* ps = (float*)smem;
#pragma unroll
    for (int nf = 0; nf < NF; ++nf) {
        float sm = 0.f, sq = 0.f;
#pragma unroll
        for (int mf = 0; mf < 2; ++mf)
#pragma unroll
            for (int r = 0; r < 4; ++r) {
                float v = acc[mf][nf][r];
                sm += v; sq += v * v;
            }
        sm += __shfl_xor(sm, 16); sq += __shfl_xor(sq, 16);
        sm += __shfl_xor(sm, 32); sq += __shfl_xor(sq, 32);
        if (lane < 16) {
            ps[(wid * 2 + 0) * BN + nf * 16 + lane] = sm;
            ps[(wid * 2 + 1) * BN + nf * 16 + lane] = sq;
        }
    }
    __syncthreads();
    if (tid < BN) {
        float sm = ps[0 * BN + tid] + ps[2 * BN + tid] + ps[4 * BN + tid] + ps[6 * BN + tid];
        float sq = ps[1 * BN + tid] + ps[3 * BN + tid] + ps[5 * BN + tid] + ps[7 * BN + tid];
        int slot = PERB ? (b * 32 + (gm & 31)) : (gm & 63);
        float* pb = part + (size_t)(gy * 64 + slot) * 2 * BN;
        atomicAdd(&pb[tid], sm);
        atomicAdd(&pb[BN + tid], sq);
    }
}

// ---------------------------------------------------------------------------
// ffn_stats_k: x2 = A3*y2+B3+xT (write global + keep in LDS), then f1 GEMM
// stats-only over 4 quarters of W1 (96 rows each). part layout [q][64][2][96].
// ---------------------------------------------------------------------------
__global__ __launch_bounds__(256)
void ffn_stats_k(const char* __restrict__ y2, const char* __restrict__ xT,
                 const float* __restrict__ cfA, const float* __restrict__ cfB,
                 const float* __restrict__ biasf1, const char* __restrict__ Wf1,
                 char* __restrict__ x2, float* __restrict__ part)
{
    __shared__ __align__(16) char smem[32768 + 24576];   // As[128][256], Bs[96][256]
    __shared__ float ps[8 * 96];
    char* As = smem;
    char* Bs = smem + 32768;

    const int tid = threadIdx.x;
    const int lane = tid & 63, wid = tid >> 6, l16 = lane & 15, lhi = lane >> 4;
    const int gm = blockIdx.x;
    const int v0 = gm * 128;

    // ---- compute x2 tile: 6 units per thread
#pragma unroll
    for (int j = 0; j < 6; ++j) {
        int slot = tid + 256 * j;
        int v = slot / 12, uc = slot % 12, cb = uc * 8;
        short8 yv = *(const short8*)(y2 + (size_t)(v0 + v) * 192 + uc * 16);
        short8 xv = *(const short8*)(xT + (size_t)(v0 + v) * 192 + uc * 16);
        f4 a0 = *(const f4*)(cfA + cb), a1 = *(const f4*)(cfA + cb + 4);
        f4 d0 = *(const f4*)(cfB + cb), d1 = *(const f4*)(cfB + cb + 4);
        short8 o;
#pragma unroll
        for (int e = 0; e < 4; ++e) {
            float t0 = fmaf(a0[e], bu2f((unsigned short)yv[e]),     d0[e]) + bu2f((unsigned short)xv[e]);
            float t1 = fmaf(a1[e], bu2f((unsigned short)yv[e + 4]), d1[e]) + bu2f((unsigned short)xv[e + 4]);
            o[e]     = (short)f2bu(t0);
            o[e + 4] = (short)f2bu(t1);
        }
        *(short8*)(x2 + (size_t)(v0 + v) * 192 + uc * 16) = o;
        *(short8*)(As + v * 256 + ((uc ^ (v & 7)) << 4)) = o;
    }

    for (int q = 0; q < 4; ++q) {
        // stage W1 quarter: 96 rows x 256B = 24 groups of 1024B
        for (int i = wid; i < 24; i += 4) {
            int o = i * 4 + (lane >> 4), u = lane & 15;
            glds16(Wf1 + (size_t)(q * 96 + o) * 192 + ((u ^ (o & 7)) << 4),
                   Bs + i * 1024);
        }
        __syncthreads();
        f4 acc[2][6];
#pragma unroll
        for (int nf = 0; nf < 6; ++nf) {
            float bb = biasf1[q * 96 + nf * 16 + l16];
            f4 t = {bb, bb, bb, bb};
            acc[0][nf] = t; acc[1][nf] = t;
        }
#pragma unroll
        for (int ks = 0; ks < 3; ++ks) {
            int kg = ks * 4 + lhi;
            short8 av[2];
#pragma unroll
            for (int mf = 0; mf < 2; ++mf) {
                int v = wid * 32 + mf * 16 + l16;
                av[mf] = *(const short8*)(As + v * 256 + ((kg ^ (v & 7)) << 4));
            }
#pragma unroll
            for (int nf = 0; nf < 6; ++nf) {
                int o = nf * 16 + l16;
                short8 bv = *(const short8*)(Bs + o * 256 + ((kg ^ (o & 7)) << 4));
                acc[0][nf] = __builtin_amdgcn_mfma_f32_16x16x32_bf16(av[0], bv, acc[0][nf], 0, 0, 0);
                acc[1][nf] = __builtin_amdgcn_mfma_f32_16x16x32_bf16(av[1], bv, acc[1][nf], 0, 0, 0);
            }
        }
        // stats
#pragma unroll
        for (int nf = 0; nf < 6; ++nf) {
            float sm = 0.f, sq = 0.f;
#pragma unroll
            for (int mf = 0; mf < 2; ++mf)
#pragma unroll
                for (int r = 0; r < 4; ++r) {
                    float v = acc[mf][nf][r];
                    sm += v; sq += v * v;
                }
            sm += __shfl_xor(sm, 16); sq += __shfl_xor(sq, 16);
            sm += __shfl_xor(sm, 32); sq += __shfl_xor(sq, 32);
            if (lane < 16) {
                ps[(wid * 2 + 0) * 96 + nf * 16 + lane] = sm;
                ps[(wid * 2 + 1) * 96 + nf * 16 + lane] = sq;
            }
        }
        __syncthreads();
        if (tid < 96) {
            float sm = ps[0 * 96 + tid] + ps[2 * 96 + tid] + ps[4 * 96 + tid] + ps[6 * 96 + tid];
            float sq = ps[1 * 96 + tid] + ps[3 * 96 + tid] + ps[5 * 96 + tid] + ps[7 * 96 + tid];
            float* pb = part + (size_t)(q * 64 + (gm & 63)) * 192;
            atomicAdd(&pb[tid], sm);
            atomicAdd(&pb[96 + tid], sq);
        }
    }
}

// ---------------------------------------------------------------------------
// ffn_k: fused f1+lrelu+BNf1+f2. Per 128-voxel block, 6 chunks of 64 y3-ch:
//   GEMM1 (swapped, D rows=ch) -> lrelu(A4*z+B4') -> zbuf (LDS, XOR) ->
//   GEMM2 accumulates y4. BNf2 stats fused. y3 never in HBM.
// ---------------------------------------------------------------------------
__global__ __launch_bounds__(256)
void ffn_k(const char* __restrict__ x2, const float* __restrict__ cfA4,
           const float* __restrict__ cfB4, const float* __restrict__ biasf2,
           const char* __restrict__ Wf1, const char* __restrict__ Wf2,
           bf16* __restrict__ y4, float* __restrict__ part)
{
    __shared__ __align__(16) char smem[32768 + 16384 + 12288 + 16384];
    char* As  = smem;                    // x2 tile [128][256B]
    char* W1c = smem + 32768;            // [64][256B]
    char* W2c = smem + 49152;            // [96][128B]
    char* zb  = smem + 61440;            // [128][128B]
    float* ps = (float*)zb;              // aliased after last GEMM2

    const int tid = threadIdx.x;
    const int lane = tid & 63, wid = tid >> 6, l16 = lane & 15, lhi = lane >> 4;
    const int gm = blockIdx.x;
    const int v0 = gm * 128;

    // stage x2 tile: 128 rows x 256B = 32 groups
    for (int i = wid; i < 32; i += 4) {
        int v = i * 4 + (lane >> 4), u = lane & 15;
        glds16(x2 + (size_t)(v0 + v) * 192 + ((u ^ (v & 7)) << 4), As + i * 1024);
    }

    f4 accY[2][6];
#pragma unroll
    for (int nf = 0; nf < 6; ++nf) {
        float bb = biasf2[nf * 16 + l16];
        f4 t = {bb, bb, bb, bb};
        accY[0][nf] = t; accY[1][nf] = t;
    }

    for (int nc = 0; nc < 6; ++nc) {
        // stage W1 chunk: 64 rows x 256B = 16 groups
        for (int i = wid; i < 16; i += 4) {
            int o = i * 4 + (lane >> 4), u = lane & 15;
            glds16(Wf1 + (size_t)(nc * 64 + o) * 192 + ((u ^ (o & 7)) << 4),
                   W1c + i * 1024);
        }
        // stage W2 K-slice: 96 rows x 128B = 12 groups
        for (int i = wid; i < 12; i += 4) {
            int o = i * 8 + (lane >> 3), u = lane & 7;
            glds16(Wf2 + (size_t)o * 768 + nc * 128 + ((u ^ (o & 7)) << 4),
                   W2c + i * 1024);
        }
        __syncthreads();
        // GEMM1 swapped: z[mt][nt], D row = chunk-channel, col = voxel
        f4 z[4][2];
#pragma unroll
        for (int mt = 0; mt < 4; ++mt)
#pragma unroll
            for (int nt = 0; nt < 2; ++nt) z[mt][nt] = {0.f, 0.f, 0.f, 0.f};
#pragma unroll
        for (int ks = 0; ks < 3; ++ks) {
            int kg = ks * 4 + lhi;
            short8 xv[2];
#pragma unroll
            for (int nt = 0; nt < 2; ++nt) {
                int v = wid * 32 + nt * 16 + l16;
                xv[nt] = *(const short8*)(As + v * 256 + ((kg ^ (v & 7)) << 4));
            }
#pragma unroll
            for (int mt = 0; mt < 4; ++mt) {
                int o = mt * 16 + l16;
                short8 wv = *(const short8*)(W1c + o * 256 + ((kg ^ (o & 7)) << 4));
                z[mt][0] = __builtin_amdgcn_mfma_f32_16x16x32_bf16(wv, xv[0], z[mt][0], 0, 0, 0);
                z[mt][1] = __builtin_amdgcn_mfma_f32_16x16x32_bf16(wv, xv[1], z[mt][1], 0, 0, 0);
            }
        }
        // lrelu(A4*z + B4') -> zbuf [v][64ch], us4 writes, XOR-swizzled
#pragma unroll
        for (int mt = 0; mt < 4; ++mt) {
            int ch = nc * 64 + mt * 16 + lhi * 4;
            f4 a = *(const f4*)(cfA4 + ch);
            f4 bb = *(const f4*)(cfB4 + ch);
#pragma unroll
            for (int nt = 0; nt < 2; ++nt) {
                int v = wid * 32 + nt * 16 + l16;
                us4 p;
#pragma unroll
                for (int r = 0; r < 4; ++r) {
                    float t = fmaf(a[r], z[mt][nt][r], bb[r]);
                    t = fmaxf(t, 0.2f * t);
                    p[r] = f2bu(t);
                }
                *(us4*)(zb + v * 128 + (((mt * 2 + (lhi >> 1)) ^ (v & 7)) << 4) + ((lhi & 1) << 3)) = p;
            }
        }
        __syncthreads();
        // GEMM2: accY += z x W2c  (K = 64)
#pragma unroll
        for (int ks = 0; ks < 2; ++ks) {
            int kg = ks * 4 + lhi;
            short8 av[2];
#pragma unroll
            for (int mf = 0; mf < 2; ++mf) {
                int v = wid * 32 + mf * 16 + l16;
                av[mf] = *(const short8*)(zb + v * 128 + ((kg ^ (v & 7)) << 4));
            }
#pragma unroll
            for (int nf = 0; nf < 6; ++nf) {
                int o = nf * 16 + l16;
                short8 bv = *(const short8*)(W2c + o * 128 + ((kg ^ (o & 7)) << 4));
                accY[0][nf] = __builtin_amdgcn_mfma_f32_16x16x32_bf16(av[0], bv, accY[0][nf], 0, 0, 0);
                accY[1][nf] = __builtin_amdgcn_mfma_f32_16x16x32_bf16(av[1], bv, accY[1][nf], 0, 0, 0);
            }
        }
        __syncthreads();
    }

    // store y4 + BNf2 stats
#pragma unroll
    for (int mf = 0; mf < 2; ++mf) {
        int vb = v0 + wid * 32 + mf * 16 + lhi * 4;
#pragma unroll
        for (int nf = 0; nf < 6; ++nf) {
            int n = nf * 16 + l16;
#pragma unroll
            for (int r = 0; r < 4; ++r) {
                bf16 o; *(unsigned short*)&o = f2bu(accY[mf][nf][r]);
                y4[(size_t)(vb + r) * 96 + n] = o;
            }
        }
    }
#pragma unroll
    for (int nf = 0; nf < 6; ++nf) {
        float sm = 0.f, sq = 0.f;
#pragma unroll
        for (int mf = 0; mf < 2; ++mf)
#pragma unroll
            for (int r = 0; r < 4; ++r) {
                float v = accY[mf][nf][r];
                sm += v; sq += v * v;
            }
        sm += __shfl_xor(sm, 16); sq += __shfl_xor(sq, 16);
        sm += __shfl_xor(sm, 32); sq += __shfl_xor(sq, 32);
        if (lane < 16) {
            ps[(wid * 2 + 0) * 96 + nf * 16 + lane] = sm;
            ps[(wid * 2 + 1) * 96 + nf * 16 + lane] = sq;
        }
    }
    __syncthreads();
    if (tid < 96) {
        float sm = ps[0 * 96 + tid] + ps[2 * 96 + tid] + ps[4 * 96 + tid] + ps[6 * 96 + tid];
        float sq = ps[1 * 96 + tid] + ps[3 * 96 + tid] + ps[5 * 96 + tid] + ps[7 * 96 + tid];
        float* pb = part + (size_t)(gm & 63) * 192;
        atomicAdd(&pb[tid], sm);
        atomicAdd(&pb[96 + tid], sq);
    }
}

// ---------------------------------------------------------------------------
// partial sums -> affine coefs  A = g*rsqrt(var+eps), B = be - m*A (+ A*bias)
// ---------------------------------------------------------------------------
__global__ void finalize_k(const float* __restrict__ part, float* __restrict__ cf,
                           const float* __restrict__ g, const float* __restrict__ be,
                           const float* __restrict__ bias,
                           int nStats, int CO, int BN, int perB, float invN)
{
    int s = blockIdx.x * 64 + threadIdx.x;
    if (s >= nStats) return;
    int ch = perB ? (s % CO) : s;
    int bb = perB ? (s / CO) : 0;
    int gy = ch / BN, c = ch - gy * BN;
    int j0 = perB ? bb * 32 : 0, cnt = perB ? 32 : 64;
    float sm = 0.f, sq = 0.f;
    for (int j = 0; j < cnt; ++j) {
        const float* pb = part + (size_t)(gy * 64 + j0 + j) * 2 * BN;
        sm += pb[c]; sq += pb[BN + c];
    }
    float m = sm * invN;
    float var = fmaf(-m, m, sq * invN);
    float A = g[ch] * rsqrtf(var + 1e-5f);
    cf[s] = A;
    float B = fmaf(-m, A, be[ch]);
    if (bias) B = fmaf(A, bias[ch], B);
    cf[1024 + s] = B;
}

// ---------------------------------------------------------------------------
// weight prep: f32 [CO][CI] -> bf16 [CO][KP] (KP in elements)
//   fc1 [96][128]@0 | g [192][192]@12288 | fc2 [96][192]@49152
//   f1 [384][96]@67584 (packed) | f2 [96][384]@104448
// ---------------------------------------------------------------------------
__global__ void wprep_k(const float* __restrict__ w0, const float* __restrict__ w1,
                        const float* __restrict__ w2, const float* __restrict__ w3,
                        const float* __restrict__ w4, bf16* __restrict__ Wb)
{
    int i = blockIdx.x * 256 + threadIdx.x;     // < 141312
    if (i >= 141312) return;
    const float* src; int r, KP, CI, off;
    if (i < 12288)       { src = w0; r = i;          KP = 128; CI = 96;  off = 0; }
    else if (i < 49152)  { src = w1; r = i - 12288;  KP = 192; CI = 192; off = 12288; }
    else if (i < 67584)  { src = w2; r = i - 49152;  KP = 192; CI = 192; off = 49152; }
    else if (i < 104448) { src = w3; r = i - 67584;  KP = 96;  CI = 96;  off = 67584; }
    else                 { src = w4; r = i - 104448; KP = 384; CI = 384; off = 104448; }
    int o = r / KP, k = r - o * KP;
    float v = (k < CI) ? src[o * CI + k] : 0.f;
    bf16 h; *(unsigned short*)&h = f2bu(v);
    Wb[off + r] = h;
}

// ---------------------------------------------------------------------------
// tin: x f32 [b][c][s] -> xT bf16 [v][96] via LDS transpose
// ---------------------------------------------------------------------------
__global__ __launch_bounds__(256)
void tin_k(const float* __restrict__ x, char* __restrict__ xT)
{
    __shared__ float ldsT[128 * 97];
    const int gm = blockIdx.x, b = gm >> 10, s0 = (gm & 1023) * 128;
    const int t = threadIdx.x;
#pragma unroll
    for (int i = 0; i < 12; ++i) {
        int idx = t + 256 * i;
        int c = idx >> 5, s4 = idx & 31;
        f4 r = *(const f4*)(x + ((size_t)(b * 96 + c) << 17) + s0 + s4 * 4);
#pragma unroll
        for (int j = 0; j < 4; ++j) ldsT[(s4 * 4 + j) * 97 + c] = r[j];
    }
    __syncthreads();
#pragma unroll
    for (int i = 0; i < 6; ++i) {
        int idx = t + 256 * i;
        int r = idx / 12, uc = idx % 12, cb = uc * 8;
        short8 o;
#pragma unroll
        for (int e = 0; e < 8; ++e) o[e] = (short)f2bu(ldsT[r * 97 + cb + e]);
        *(short8*)(xT + (size_t)(b * Sq + s0 + r) * 192 + uc * 16) = o;
    }
}

// ---------------------------------------------------------------------------
// MR pass 1a: dminp[b][h][w][dh][p][c] = raw min over d in half dh, parity p
// ---------------------------------------------------------------------------
__global__ __launch_bounds__(192)
void mr_dmin_k(const char* __restrict__ y1, char* __restrict__ dminp)
{
    const int wq = blockIdx.x >> 1, dh = blockIdx.x & 1;
    const int h = blockIdx.y, b = blockIdx.z;
    const int t = threadIdx.x;
    const int w = wq * 16 + t / 12, uc = t % 12;
    const char* base = y1 + (size_t)(b * Sq + dh * 16 * 4096 + h * 64 + w) * 192 + uc * 16;
    float mn[2][8];
#pragma unroll
    for (int p = 0; p < 2; ++p)
#pragma unroll
        for (int e = 0; e < 8; ++e) mn[p][e] = 1e30f;
#pragma unroll 4
    for (int i = 0; i < 16; ++i) {
        short8 raw = *(const short8*)(base + (size_t)i * (4096 * 192));
        int p = i & 1;
#pragma unroll
        for (int e = 0; e < 8; ++e)
            mn[p][e] = fminf(mn[p][e], bu2f((unsigned short)raw[e]));
    }
#pragma unroll
    for (int p = 0; p < 2; ++p) {
        short8 o;
#pragma unroll
        for (int e = 0; e < 8; ++e) o[e] = (short)f2bu(mn[p][e]);
        *(short8*)(dminp + (size_t)((((b * 64 + h) * 64 + w) * 2 + dh) * 2 + p) * 192 + uc * 16) = o;
    }
}

// ---------------------------------------------------------------------------
// MR pass 1b: hminp[b][d][w][hq][p][c] = raw min over h in quarter hq, parity p
// ---------------------------------------------------------------------------
__global__ __launch_bounds__(192)
void mr_hmin_k(const char* __restrict__ y1, char* __restrict__ hminp)
{
    const int wq = blockIdx.x >> 2, hq = blockIdx.x & 3;
    const int d = blockIdx.y, b = blockIdx.z;
    const int t = threadIdx.x;
    const int w = wq * 16 + t / 12, uc = t % 12;
    const char* base = y1 + (size_t)(b * Sq + d * 4096 + hq * 16 * 64 + w) * 192 + uc * 16;
    float mn[2][8];
#pragma unroll
    for (int p = 0; p < 2; ++p)
#pragma unroll
        for (int e = 0; e < 8; ++e) mn[p][e] = 1e30f;
#pragma unroll 4
    for (int i = 0; i < 16; ++i) {
        short8 raw = *(const short8*)(base + (size_t)i * (64 * 192));
        int p = i & 1;
#pragma unroll
        for (int e = 0; e < 8; ++e)
            mn[p][e] = fminf(mn[p][e], bu2f((unsigned short)raw[e]));
    }
#pragma unroll
    for (int p = 0; p < 2; ++p) {
        short8 o;
#pragma unroll
        for (int e = 0; e < 8; ++e) o[e] = (short)f2bu(mn[p][e]);
        *(short8*)(hminp + (size_t)((((b * 32 + d) * 64 + w) * 4 + hq) * 2 + p) * 192 + uc * 16) = o;
    }
}

// ---------------------------------------------------------------------------
// MR pass 2: xj = A_c * (y1 - min(dminp x2, hminp x4, wmin))
// ---------------------------------------------------------------------------
__global__ __launch_bounds__(256)
void mr_p2_k(const char* __restrict__ y1, const float* __restrict__ cfA,
             const char* __restrict__ dminp, const char* __restrict__ hminp,
             char* __restrict__ xj)
{
    __shared__ __align__(16) char rowb[64 * 96 * 2];
    __shared__ float wlds[2 * 96];
    const int h = blockIdx.x, d = blockIdx.y, b = blockIdx.z;
    const int t = threadIdx.x;

    short8 hv[3];
#pragma unroll
    for (int j = 0; j < 3; ++j) {
        int slot = t + 256 * j;
        int w = slot / 12, uc = slot % 12;
        short8 raw = *(const short8*)(y1 + (size_t)(b * Sq + d * 4096 + h * 64 + w) * 192 + uc * 16);
        hv[j] = raw;
        *(short8*)(rowb + slot * 16) = raw;
    }
    __syncthreads();
    if (t < 192) {
        int p = t / 96, c = t % 96;
        float m = 1e30f;
        for (int w2 = p; w2 < 64; w2 += 2)
            m = fminf(m, bu2f(*(const unsigned short*)(rowb + (w2 * 96 + c) * 2)));
        wlds[t] = m;
    }
    __syncthreads();
#pragma unroll
    for (int j = 0; j < 3; ++j) {
        int slot = t + 256 * j;
        int w = slot / 12, uc = slot % 12, cb = uc * 8;
        const char* dp = dminp + (size_t)((((b * 64 + h) * 64 + w) * 2) * 2 + (d & 1)) * 192 + uc * 16;
        short8 dm0 = *(const short8*)(dp);
        short8 dm1 = *(const short8*)(dp + 384);
        const char* hp = hminp + (size_t)((((b * 32 + d) * 64 + w) * 4) * 2 + (h & 1)) * 192 + uc * 16;
        short8 hm0 = *(const short8*)(hp);
        short8 hm1 = *(const short8*)(hp + 384);
        short8 hm2 = *(const short8*)(hp + 768);
        short8 hm3 = *(const short8*)(hp + 1152);
        f4 a0 = *(const f4*)(cfA + cb), a1 = *(const f4*)(cfA + cb + 4);
        short8 xo;
#pragma unroll
        for (int e = 0; e < 8; ++e) {
            float m = fminf(
                fminf(bu2f((unsigned short)dm0[e]), bu2f((unsigned short)dm1[e])),
                fminf(fminf(fminf(bu2f((unsigned short)hm0[e]), bu2f((unsigned short)hm1[e])),
                            fminf(bu2f((unsigned short)hm2[e]), bu2f((unsigned short)hm3[e]))),
                      wlds[(w & 1) * 96 + cb + e]));
            float A = (e < 4) ? a0[e] : a1[e - 4];
            xo[e] = (short)f2bu(A * (bu2f((unsigned short)hv[j][e]) - m));
        }
        *(short8*)(xj + (size_t)(b * Sq + d * 4096 + h * 64 + w) * 192 + uc * 16) = xo;
    }
}

// ---------------------------------------------------------------------------
// tout: out f32 [b][c][s] = A5*y4 + B5 + x2   (transpose via LDS)
// ---------------------------------------------------------------------------
__global__ __launch_bounds__(256)
void tout_k(const char* __restrict__ y4, const float* __restrict__ cfA,
            const float* __restrict__ cfB, const char* __restrict__ x2,
            float* __restrict__ outp)
{
    __shared__ float ldsT[128 * 97];
    const int gm = blockIdx.x, b = gm >> 10, s0 = (gm & 1023) * 128;
    const int t = threadIdx.x;
#pragma unroll
    for (int i = 0; i < 6; ++i) {
        int idx = t + 256 * i;
        int r = idx / 12, uc = idx % 12, cb = uc * 8;
        size_t vv = (size_t)(b * Sq + s0 + r);
        short8 yv = *(const short8*)(y4 + vv * 192 + uc * 16);
        short8 xv = *(const short8*)(x2 + vv * 192 + uc * 16);
        f4 a0 = *(const f4*)(cfA + cb), a1 = *(const f4*)(cfA + cb + 4);
        f4 d0 = *(const f4*)(cfB + cb), d1 = *(const f4*)(cfB + cb + 4);
#pragma unroll
        for (int e = 0; e < 4; ++e) {
            ldsT[r * 97 + cb + e]     = fmaf(a0[e], bu2f((unsigned short)yv[e]),     d0[e]) + bu2f((unsigned short)xv[e]);
            ldsT[r * 97 + cb + e + 4] = fmaf(a1[e], bu2f((unsigned short)yv[e + 4]), d1[e]) + bu2f((unsigned short)xv[e + 4]);
        }
    }
    __syncthreads();
#pragma unroll
    for (int i = 0; i < 12; ++i) {
        int idx = t + 256 * i;
        int c = idx >> 5, s4 = idx & 31;
        f4 o;
#pragma unroll
        for (int j = 0; j < 4; ++j) o[j] = ldsT[(s4 * 4 + j) * 97 + c];
        *(f4*)(outp + ((size_t)(b * 96 + c) << 17) + s0 + s4 * 4) = o;
    }
}

// ===========================================================================
extern "C" void kernel_launch(void* const* d_in, const int* in_sizes, int n_in,
                              void* d_out, int out_size, void* d_ws, size_t ws_size,
                              hipStream_t stream)
{
    (void)in_sizes; (void)n_in; (void)out_size; (void)ws_size;

    const float* x      = (const float*)d_in[0];
    const float* w_fc1  = (const float*)d_in[1];
    const float* b_fc1  = (const float*)d_in[2];
    const float* g_bn1  = (const float*)d_in[3];
    const float* be_bn1 = (const float*)d_in[4];
    const float* w_g    = (const float*)d_in[5];
    const float* b_g    = (const float*)d_in[6];
    const float* g_in   = (const float*)d_in[7];
    const float* be_in  = (const float*)d_in[8];
    const float* w_fc2  = (const float*)d_in[9];
    const float* b_fc2  = (const float*)d_in[10];
    const float* g_bn2  = (const float*)d_in[11];
    const float* be_bn2 = (const float*)d_in[12];
    const float* w_f1   = (const float*)d_in[13];
    const float* b_f1   = (const float*)d_in[14];
    const float* g_bnf1 = (const float*)d_in[15];
    const float* be_bnf1= (const float*)d_in[16];
    const float* w_f2   = (const float*)d_in[17];
    const float* b_f2   = (const float*)d_in[18];
    const float* g_bnf2 = (const float*)d_in[19];
    const float* be_bnf2= (const float*)d_in[20];
    float* outp = (float*)d_out;

    char* W = (char*)d_ws;
    char* xT    = W;
    char* y1    = W + 50331648ull;
    char* dminp = W + 100663296ull;
    char* hminp = W + 113246208ull;
    char* xj    = W + 125829120ull;
    char* yg    = W + 176160768ull;
    char* y2    = W + 50331648ull;     // reuse y1 slot (y1 dead after conv g)
    char* y4    = W + 201326592ull;
    char* x2    = W + 251658240ull;
    char* M     = W + 301989888ull;
    bf16*  Wb   = (bf16*)M;               // 282624 B
    float* cf   = (float*)(M + 307200);   // 5 slots x 2048 f32
    float* part = (float*)(M + 348160);   // 5 slots x 49152 f32

    hipMemsetAsync(part, 0, 5 * 196608, stream);

    const float invBN = 1.f / (float)NVq, invIN = 1.f / (float)Sq;
    dim3 blk(256);
    float* c1 = cf, *c2 = cf + 2048, *c3 = cf + 4096, *c4 = cf + 6144, *c5 = cf + 8192;
    const char* Wfc1 = (const char*)Wb;
    const char* Wg   = (const char*)Wb + 24576;
    const char* Wfc2 = (const char*)Wb + 98304;
    const char* Wf1  = (const char*)Wb + 135168;
    const char* Wf2  = (const char*)Wb + 208896;

    wprep_k<<<552, blk, 0, stream>>>(w_fc1, w_g, w_fc2, w_f1, w_f2, Wb);
    tin_k<<<2048, blk, 0, stream>>>(x, xT);

    // fc1: 96 -> 96 (plain, gload_lds)
    conv_k<192, 128, 96, 96, 0, false><<<dim3(2048, 1), blk, 0, stream>>>(
        xT, nullptr, Wfc1, b_fc1, nullptr, nullptr, (bf16*)y1, part);
    finalize_k<<<2, 64, 0, stream>>>(part, c1, g_bn1, be_bn1, nullptr, 96, 96, 96, 0, invBN);

    // MRConv on raw y1 (A>0): partial mins, then xj = A*(y1 - min3)
    mr_dmin_k<<<dim3(8, 64, 2), dim3(192), 0, stream>>>(y1, dminp);
    mr_hmin_k<<<dim3(16, 32, 2), dim3(192), 0, stream>>>(y1, hminp);
    mr_p2_k<<<dim3(64, 32, 2), blk, 0, stream>>>(y1, c1, dminp, hminp, xj);

    // grapher conv: concat(y1-affine, xj) 192 -> 192, IN stats per (b,c)
    conv_k<192, 192, 192, 192, 4, true><<<dim3(2048, 1), blk, 0, stream>>>(
        y1, xj, Wg, b_g, c1, c1 + 1024, (bf16*)yg, part + 49152);
    finalize_k<<<6, 64, 0, stream>>>(part + 49152, c2, g_in, be_in, nullptr, 384, 192, 192, 1, invIN);

    // fc2: 192 -> 96, loader = lrelu(A2*yg+B2) per (b,c)
    conv_k<384, 192, 96, 96, 2, false><<<dim3(2048, 1), blk, 0, stream>>>(
        yg, nullptr, Wfc2, b_fc2, c2, c2 + 1024, (bf16*)y2, part + 98304);
    finalize_k<<<2, 64, 0, stream>>>(part + 98304, c3, g_bn2, be_bn2, nullptr, 96, 96, 96, 0, invBN);

    // FFN phase 1: x2 = A3*y2+B3+xT (write) + f1 stats-only -> BNf1 partials
    ffn_stats_k<<<2048, blk, 0, stream>>>(y2, xT, c3, c3 + 1024, b_f1, Wf1, x2, part + 147456);
    finalize_k<<<6, 64, 0, stream>>>(part + 147456, c4, g_bnf1, be_bnf1, b_f1, 384, 384, 96, 0, invBN);

    // FFN phase 2: fused f1+lrelu+f2 -> y4 + BNf2 partials
    ffn_k<<<2048, blk, 0, stream>>>(x2, c4, c4 + 1024, b_f2, Wf1, Wf2, (bf16*)y4, part + 196608);
    finalize_k<<<2, 64, 0, stream>>>(part + 196608, c5, g_bnf2, be_bnf2, nullptr, 96, 96, 96, 0, invBN);

    tout_k<<<2048, blk, 0, stream>>>(y4, c5, c5 + 1024, x2, outp);
}